// Round 5
// baseline (183.277 us; speedup 1.0000x reference)
//
#include <hip/hip_runtime.h>
#include <hip/hip_bf16.h>
#include <math.h>

typedef __bf16 bf16x8 __attribute__((ext_vector_type(8)));
typedef float f32x4 __attribute__((ext_vector_type(4)));

#define NB 2
#define NS 1024
#define ND 1024
#define NH 8
#define NQK 512
#define NV 1024
#define DQK 64
#define DHV 128
#define CHUNK 64
#define NCHUNK 16

#define GLDS16(g, l) __builtin_amdgcn_global_load_lds((const __attribute__((address_space(1))) void*)(g), (__attribute__((address_space(3))) void*)(l), 16, 0, 0)

static __device__ __forceinline__ void split_bf16(float v, __bf16& hi, __bf16& lo) {
  hi = (__bf16)v;
  lo = (__bf16)(v - (float)hi);
}
static __device__ __forceinline__ unsigned short bf2u(__bf16 v) {
  union { __bf16 b; unsigned short u; } c; c.b = v; return c.u;
}
static __device__ __forceinline__ unsigned short hf2u(_Float16 v) {
  union { _Float16 h; unsigned short u; } c; c.h = v; return c.u;
}

// bijective XCD swizzle (m204)
static __device__ __forceinline__ int xcd_swz(int orig, int nwg) {
  int q = nwg >> 3, r = nwg & 7;
  int xcd = orig & 7, idx = orig >> 3;
  int base = (xcd < r) ? xcd * (q + 1) : r * (q + 1) + (xcd - r) * q;
  return base + idx;
}

// ---------------- fused f32 -> bf16 conversion (all 6 tensors, 1 launch) ----------------
__global__ __launch_bounds__(256) void cvt_all(const float* __restrict__ x,
    const float* __restrict__ wq, const float* __restrict__ wk,
    const float* __restrict__ wv, const float* __restrict__ wog,
    const float* __restrict__ wout,
    __bf16* __restrict__ xb, __bf16* __restrict__ wb, __bf16* __restrict__ wob) {
  long i = (long)blockIdx.x * 256 + threadIdx.x;   // float4 index
  const float* src; __bf16* dst;
  if (i < 524288)        { src = x    + i*4;                    dst = xb  + i*4; }
  else if (i < 655360)   { long j = i -  524288; src = wq  + j*4; dst = wb + j*4; }
  else if (i < 786432)   { long j = i -  655360; src = wk  + j*4; dst = wb +  524288 + j*4; }
  else if (i < 1048576)  { long j = i -  786432; src = wv  + j*4; dst = wb + 1048576 + j*4; }
  else if (i < 1310720)  { long j = i - 1048576; src = wog + j*4; dst = wb + 2097152 + j*4; }
  else                   { long j = i - 1310720; src = wout+ j*4; dst = wob + j*4; }
  float4 v = *(const float4*)src;
  __bf16 o[4];
  o[0] = (__bf16)v.x; o[1] = (__bf16)v.y; o[2] = (__bf16)v.z; o[3] = (__bf16)v.w;
  *(short4*)dst = *(const short4*)o;
}

// ---------------- staging macro shared by both GEMMs ----------------
#define GEMM_STAGE(Abuf, Bbuf, Aptr, Bptr, Krun, ktv)                         \
  do {                                                                        \
    _Pragma("unroll")                                                         \
    for (int i_ = 0; i_ < 4; ++i_) {                                          \
      const int sb_ = i_ * 256 + wid * 64;                                    \
      const int s_ = sb_ + lane;                                              \
      const int row_ = s_ >> 3;                                               \
      const int klog_ = (s_ & 7) ^ (row_ & 7);                                \
      GLDS16(Aptr + (size_t)(m0 + row_) * Krun + (ktv) * 64 + klog_ * 8, Abuf + sb_ * 8); \
      GLDS16(Bptr + (size_t)(n0 + row_) * Krun + (ktv) * 64 + klog_ * 8, Bbuf + sb_ * 8); \
    }                                                                         \
  } while (0)

// ---------------- generic bf16 GEMM, C[M,N] = A[M,K]*B[N,K]^T, f32 out ----------------
__global__ __launch_bounds__(256) void gemm_bt(const __bf16* __restrict__ A,
                                               const __bf16* __restrict__ Bm,
                                               float* __restrict__ C,
                                               int M, int N, int K, int ntn, int nwg) {
  __shared__ __bf16 smA[2][128 * 64];
  __shared__ __bf16 smB[2][128 * 64];
  const int wg = xcd_swz(blockIdx.x, nwg);
  const int m0 = (wg / ntn) * 128;
  const int n0 = (wg % ntn) * 128;
  const int tid = threadIdx.x;
  const int wid = tid >> 6, lane = tid & 63;
  const int wm = (wid >> 1) * 64, wn = (wid & 1) * 64;
  const int fr = lane & 15;
  const int g  = lane >> 4;
  f32x4 acc[4][4] = {};
  const int NT = K >> 6;
  GEMM_STAGE(smA[0], smB[0], A, Bm, K, 0);
  int cur = 0;
  for (int kt = 0; kt < NT; ++kt) {
    __syncthreads();
    if (kt + 1 < NT) GEMM_STAGE(smA[cur ^ 1], smB[cur ^ 1], A, Bm, K, kt + 1);
    #pragma unroll
    for (int kk = 0; kk < 2; ++kk) {
      const int kg = kk * 4 + g;
      bf16x8 af[4], bfv[4];
      #pragma unroll
      for (int f = 0; f < 4; ++f) {
        const int Ra = wm + f * 16 + fr;
        const int Rb = wn + f * 16 + fr;
        af[f]  = *(const bf16x8*)&smA[cur][Ra * 64 + ((kg ^ (Ra & 7)) * 8)];
        bfv[f] = *(const bf16x8*)&smB[cur][Rb * 64 + ((kg ^ (Rb & 7)) * 8)];
      }
      #pragma unroll
      for (int i = 0; i < 4; ++i)
        #pragma unroll
        for (int j = 0; j < 4; ++j)
          acc[i][j] = __builtin_amdgcn_mfma_f32_16x16x32_bf16(af[i], bfv[j], acc[i][j], 0, 0, 0);
    }
    cur ^= 1;
  }
  const int orow = m0 + wm + g * 4;
  const int ocol = n0 + wn + fr;
  #pragma unroll
  for (int i = 0; i < 4; ++i)
    #pragma unroll
    for (int j = 0; j < 4; ++j)
      #pragma unroll
      for (int r = 0; r < 4; ++r)
        C[(size_t)(orow + i*16 + r) * N + (ocol + j*16)] = acc[i][j][r];
}

// ---------------- projection GEMM with format-aware epilogue ----------------
// cols 0-511 -> q (x0.125 hi/lo, swz), 512-1023 -> k (hi/lo swz + kT), 1024-2047 -> vT,
// 2048-3071 -> sigmoid f16. q/k/og go through a 64KB LDS bounce for 16B coalesced stores.
__global__ __launch_bounds__(256) void gemm_proj(const __bf16* __restrict__ A,
    const __bf16* __restrict__ Bm,
    __bf16* __restrict__ qh, __bf16* __restrict__ ql,
    __bf16* __restrict__ kh, __bf16* __restrict__ kl,
    __bf16* __restrict__ kT, __bf16* __restrict__ vT,
    _Float16* __restrict__ ogs) {
  __shared__ __align__(16) char smbuf[65536];
  __bf16* const smAb = (__bf16*)smbuf;             // [2][8192]
  __bf16* const smBb = (__bf16*)(smbuf + 32768);   // [2][8192]
  const int wg = xcd_swz(blockIdx.x, 384);
  const int m0 = (wg / 24) * 128;
  const int n0 = (wg % 24) * 128;
  const int tid = threadIdx.x;
  const int wid = tid >> 6, lane = tid & 63;
  const int wm = (wid >> 1) * 64, wn = (wid & 1) * 64;
  const int fr = lane & 15;
  const int g  = lane >> 4;
  f32x4 acc[4][4] = {};
  GEMM_STAGE(smAb, smBb, A, Bm, 1024, 0);
  int cur = 0;
  for (int kt = 0; kt < 16; ++kt) {
    __syncthreads();
    if (kt + 1 < 16) GEMM_STAGE(smAb + (cur^1)*8192, smBb + (cur^1)*8192, A, Bm, 1024, kt + 1);
    #pragma unroll
    for (int kk = 0; kk < 2; ++kk) {
      const int kg = kk * 4 + g;
      bf16x8 af[4], bfv[4];
      #pragma unroll
      for (int f = 0; f < 4; ++f) {
        const int Ra = wm + f * 16 + fr;
        const int Rb = wn + f * 16 + fr;
        af[f]  = *(const bf16x8*)&smAb[cur*8192 + Ra * 64 + ((kg ^ (Ra & 7)) * 8)];
        bfv[f] = *(const bf16x8*)&smBb[cur*8192 + Rb * 64 + ((kg ^ (Rb & 7)) * 8)];
      }
      #pragma unroll
      for (int i = 0; i < 4; ++i)
        #pragma unroll
        for (int j = 0; j < 4; ++j)
          acc[i][j] = __builtin_amdgcn_mfma_f32_16x16x32_bf16(af[i], bfv[j], acc[i][j], 0, 0, 0);
    }
    cur ^= 1;
  }
  const int orow = m0 + wm + g * 4;
  const int ocol = n0 + wn + fr;
  const int rng = n0 >> 9;   // 0: q, 1: k, 2..3: v, 4..5: og
  if (rng == 2 || rng == 3) {
    // vT direct (8B-granule, transposed-swizzled) — unchanged
    #pragma unroll
    for (int i = 0; i < 4; ++i)
      #pragma unroll
      for (int j = 0; j < 4; ++j) {
        const int col = (ocol + j*16) & 1023;
        const int u = col & 127;
        __bf16 t4[4];
        #pragma unroll
        for (int r = 0; r < 4; ++r) t4[r] = (__bf16)acc[i][j][r];
        const int row0r = orow + i*16;
        const int bh = ((row0r >> 10) << 3) + (col >> 7);
        const int c = (row0r >> 6) & 15;
        const int s0 = (row0r & 63);
        const int off = ((bh*16 + c)*128 + u)*64 + (((s0>>3) ^ (u&7)) << 3) + (s0 & 7);
        *(short4*)&vT[off] = *(const short4*)t4;
      }
  } else {
    if (rng == 1) {
      // kT direct (8B-granule) from acc
      #pragma unroll
      for (int i = 0; i < 4; ++i)
        #pragma unroll
        for (int j = 0; j < 4; ++j) {
          const int col = (ocol + j*16) & 511;
          const int d = col & 63;
          __bf16 t4[4];
          #pragma unroll
          for (int r = 0; r < 4; ++r) t4[r] = (__bf16)acc[i][j][r];
          const int row0r = orow + i*16;
          const int bh = ((row0r >> 10) << 3) + (col >> 6);
          const int c = (row0r >> 6) & 15;
          const int s0 = (row0r & 63);
          const int off = ((bh*16 + c)*64 + d)*64 + (((s0>>3) ^ (d&7)) << 3) + (s0 & 7);
          *(short4*)&kT[off] = *(const short4*)t4;
        }
    }
    // ---- LDS bounce: pack (hi,lo) or (f16,0) then re-read coalesced ----
    __syncthreads();                       // staging LDS now dead
    ushort2* bounce = (ushort2*)smbuf;     // [128][128], col XOR-swizzled by row
    const float sc = (rng == 0) ? 0.125f : 1.0f;
    #pragma unroll
    for (int i = 0; i < 4; ++i)
      #pragma unroll
      for (int j = 0; j < 4; ++j)
        #pragma unroll
        for (int r = 0; r < 4; ++r) {
          const int lrow = wm + i*16 + g*4 + r;
          const int lcol = wn + j*16 + fr;
          ushort2 pk;
          if (rng < 2) {
            __bf16 hi, lo; split_bf16(acc[i][j][r] * sc, hi, lo);
            pk.x = bf2u(hi); pk.y = bf2u(lo);
          } else {
            _Float16 sg = (_Float16)(1.f / (1.f + __expf(-acc[i][j][r])));
            pk.x = hf2u(sg); pk.y = 0;
          }
          bounce[lrow*128 + (lcol ^ ((lrow & 7) << 3))] = pk;
        }
    __syncthreads();
    const int rrow = tid >> 1;
    const int rbase = (tid & 1) * 8;       // chunk half: 0..7 or 8..15
    const int grow = m0 + rrow;
    #pragma unroll
    for (int b8 = 0; b8 < 8; ++b8) {
      const int cc = rbase + b8;
      const int a = rrow*128 + ((cc ^ (rrow & 7)) << 3);
      ushort2 p8[8];
      *(float4*)&p8[0] = *(const float4*)&bounce[a];
      *(float4*)&p8[4] = *(const float4*)&bounce[a + 4];
      unsigned short hi8[8], lo8[8];
      #pragma unroll
      for (int z = 0; z < 8; ++z) { hi8[z] = p8[z].x; lo8[z] = p8[z].y; }
      const int coll = cc * 8;
      if (rng < 2) {
        const int colt = (n0 & 511) + coll;
        const int d8 = (colt & 63) >> 3;
        const int hb = colt & ~63;
        __bf16* Hb = (rng == 0) ? qh : kh;
        __bf16* Lb = (rng == 0) ? ql : kl;
        const size_t off = (size_t)grow*512 + hb + ((d8 ^ (grow & 7)) << 3);
        *(float4*)&Hb[off] = *(const float4*)hi8;
        *(float4*)&Lb[off] = *(const float4*)lo8;
      } else {
        const int colt = (n0 & 1023) + coll;
        *(float4*)&ogs[(size_t)grow*1024 + colt] = *(const float4*)hi8;
      }
    }
  }
}

// ---------------- i/f gate pre-activations (full f32) ----------------
__global__ __launch_bounds__(256) void ifgate_kernel(const float* __restrict__ x,
    const float* __restrict__ Wi, const float* __restrict__ bi,
    const float* __restrict__ Wf, const float* __restrict__ bf_,
    float* __restrict__ icap, float* __restrict__ flog) {
  const int row = blockIdx.x;
  const int w = threadIdx.x >> 6;
  const int l = threadIdx.x & 63;
  const float* xr = x + (size_t)row * ND;
  float xv[16];
  #pragma unroll
  for (int t = 0; t < 16; ++t) xv[t] = xr[l + 64*t];
  for (int hh = 0; hh < 2; ++hh) {
    int h = w*2 + hh;
    const float* wi = Wi + (size_t)h * ND;
    const float* wf = Wf + (size_t)h * ND;
    float si = 0.f, sf = 0.f;
    #pragma unroll
    for (int t = 0; t < 16; ++t) {
      si += xv[t] * wi[l + 64*t];
      sf += xv[t] * wf[l + 64*t];
    }
    #pragma unroll
    for (int off = 32; off; off >>= 1) {
      si += __shfl_xor(si, off, 64);
      sf += __shfl_xor(sf, off, 64);
    }
    if (l == 0) {
      float ic = 15.f * tanhf((si + bi[h]) * (1.f/15.f));
      float fc = 15.f * tanhf((sf + bf_[h]) * (1.f/15.f));
      float fl = (fc >= 0.f) ? -log1pf(__expf(-fc)) : (fc - log1pf(__expf(fc)));
      icap[row*NH + h] = ic;
      flog[row*NH + h] = fl;
    }
  }
}

// ---------------- gate scan: per (b,h), chunked cumsum/cummax ----------------
__global__ __launch_bounds__(64) void gates_kernel(const float* __restrict__ icap,
    const float* __restrict__ flog, float* __restrict__ g_g, float* __restrict__ a_g,
    float* __restrict__ m_g, float* __restrict__ m0g) {
  const int bh = blockIdx.x;
  const int b = bh >> 3, h = bh & 7;
  const int l = threadIdx.x;
  float m0 = 0.f;
  for (int c = 0; c < NCHUNK; ++c) {
    const int t = c*CHUNK + l;
    const int row = b*NS + t;
    float B = flog[row*NH + h];
    float iv = icap[row*NH + h];
    #pragma unroll
    for (int d = 1; d < 64; d <<= 1) {
      float o = __shfl_up(B, d, 64);
      if (l >= d) B += o;
    }
    float g = iv - B;
    float cm = g;
    #pragma unroll
    for (int d = 1; d < 64; d <<= 1) {
      float o = __shfl_up(cm, d, 64);
      if (l >= d) cm = fmaxf(cm, o);
    }
    float a = fmaxf(m0, cm);
    float m = B + a;
    const int idx = bh*NS + t;
    g_g[idx] = g; a_g[idx] = a; m_g[idx] = m;
    if (l == 0) m0g[bh*NCHUNK + c] = m0;
    m0 = __shfl(m, 63, 64);
  }
}

// ---------------- per-chunk U^T[u][d] = sum_s v[s][u] (w_s k[s][d]) via MFMA ----------------
__global__ __launch_bounds__(256) void u_kernel(const __bf16* __restrict__ kT,
    const __bf16* __restrict__ vT, const float* __restrict__ g_g,
    const float* __restrict__ a_g, float* __restrict__ Ut, float* __restrict__ Ung) {
  __shared__ __bf16 kts[64 * 64];
  __shared__ __bf16 vts[128 * 64];
  __shared__ float w_l[64];
  const int task = blockIdx.x;
  const int bh = task >> 4, c = task & 15;
  const int t = threadIdx.x;
  const int wid = t >> 6, lane = t & 63;
  const int fr = lane & 15, g = lane >> 4;
  if (t < 64) {
    const float aL = a_g[bh*NS + c*CHUNK + 63];
    w_l[t] = __expf(g_g[bh*NS + c*CHUNK + t] - aL);
  }
  {
    const int sb = wid * 64;
    #pragma unroll
    for (int i = 0; i < 2; ++i) {
      const int s = i*256 + sb + lane;
      GLDS16(kT + (size_t)task*4096 + s*8, kts + (i*256 + sb)*8);
    }
    #pragma unroll
    for (int i = 0; i < 4; ++i) {
      const int s = i*256 + sb + lane;
      GLDS16(vT + (size_t)task*8192 + s*8, vts + (i*256 + sb)*8);
    }
  }
  __syncthreads();
  f32x4 acc[8] = {};
  #pragma unroll
  for (int kk = 0; kk < 2; ++kk) {
    const int kg = kk*4 + g;
    const int Ra = wid*16 + fr;
    bf16x8 afr = *(const bf16x8*)&kts[Ra*64 + ((kg ^ (Ra & 7)) * 8)];
    bf16x8 afw;
    #pragma unroll
    for (int j = 0; j < 8; ++j) afw[j] = (__bf16)((float)afr[j] * w_l[kg*8 + j]);
    #pragma unroll
    for (int nt = 0; nt < 8; ++nt) {
      const int Rb = nt*16 + fr;
      bf16x8 bv = *(const bf16x8*)&vts[Rb*64 + ((kg ^ (Rb & 7)) * 8)];
      acc[nt] = __builtin_amdgcn_mfma_f32_16x16x32_bf16(afw, bv, acc[nt], 0, 0, 0);
    }
  }
  float* ub = Ut + (size_t)task * 8192;
  #pragma unroll
  for (int nt = 0; nt < 8; ++nt) {
    const int u = nt*16 + fr;
    *(f32x4*)&ub[u*64 + wid*16 + g*4] = acc[nt];
  }
  if (t < 64) {
    float s = 0.f;
    #pragma unroll
    for (int blk = 0; blk < 8; ++blk) {
      bf16x8 kv = *(const bf16x8*)&kts[t*64 + ((blk ^ (t & 7)) * 8)];
      #pragma unroll
      for (int j = 0; j < 8; ++j) s += (float)kv[j] * w_l[blk*8 + j];
    }
    Ung[task*64 + t] = s;
  }
}

// ---------------- inter-chunk state prefix scan (spread across all CUs) ----------------
__global__ __launch_bounds__(64) void statescan_kernel(const float* __restrict__ Ut,
    const float* __restrict__ Ung, const float* __restrict__ m0g,
    const float* __restrict__ a_g, __bf16* __restrict__ C0T, float* __restrict__ n0g) {
  const int bh = blockIdx.x >> 4, part = blockIdx.x & 15;
  const int e8 = part*64 + threadIdx.x;      // 0..1023: group of 8 d for one u
  const int u = e8 >> 3, d8 = e8 & 7;
  const int dsto = u*64 + ((d8 ^ (u & 7)) << 3);
  const int srco = u*64 + d8*8;
  float scale[NCHUNK];
  #pragma unroll
  for (int c = 0; c < NCHUNK; ++c)
    scale[c] = __expf(m0g[bh*NCHUNK + c] - a_g[bh*NS + c*CHUNK + 63]);
  float val[8] = {};
  for (int c = 0; c < NCHUNK; ++c) {
    const size_t base = ((size_t)(bh*NCHUNK + c)) * 8192;
    __bf16 o[8];
    #pragma unroll
    for (int j = 0; j < 8; ++j) o[j] = (__bf16)val[j];
    *(float4*)&C0T[base + dsto] = *(const float4*)o;
    f32x4 u0 = *(const f32x4*)&Ut[base + srco];
    f32x4 u1 = *(const f32x4*)&Ut[base + srco + 4];
    #pragma unroll
    for (int j = 0; j < 4; ++j) {
      val[j]   = scale[c]*val[j]   + u0[j];
      val[j+4] = scale[c]*val[j+4] + u1[j];
    }
  }
  if (part == 0) {
    float nv = 0.f;
    for (int c = 0; c < NCHUNK; ++c) {
      int idx = (bh*NCHUNK + c)*64 + threadIdx.x;
      n0g[idx] = nv;
      nv = scale[c]*nv + Ung[idx];
    }
  }
}

// ---------------- intra-chunk attention + inter + denom + LN + gate (MFMA, GLDS-staged) ----------------
__global__ __launch_bounds__(256) void intra_kernel(
    const __bf16* __restrict__ qh, const __bf16* __restrict__ ql,
    const __bf16* __restrict__ kh, const __bf16* __restrict__ kl,
    const __bf16* __restrict__ vT, const __bf16* __restrict__ C0T,
    const _Float16* __restrict__ ogs,
    const float* __restrict__ g_g, const float* __restrict__ a_g,
    const float* __restrict__ m_g, const float* __restrict__ m0g,
    const float* __restrict__ n0g,
    const float* __restrict__ gamma, __bf16* __restrict__ hout) {
  __shared__ __bf16 qh_s[32*64], ql_s[32*64];
  __shared__ __bf16 kh_s[64*64], kl_s[64*64];
  __shared__ __bf16 vt_s[128*64];
  __shared__ __bf16 c0_s[128*64];
  __shared__ __bf16 Ps[32*72];
  __shared__ float g_l[64], n0_l[64], a_l[32], m_l[32], cI_l[32];
  __shared__ float qnA[2][32], qnI_l[32], lnS[2][32], lnQ[2][32];

  const int blk = blockIdx.x;
  const int task = blk >> 1, jhalf = blk & 1;
  const int bh = task >> 4, c = task & 15;
  const int b = bh >> 3, h = bh & 7;
  const int t = threadIdx.x;
  const int wid = t >> 6, lane = t & 63;
  const int fr = lane & 15, lg = lane >> 4;
  const int jt_local = wid >> 1, half = wid & 1;
  const int jtg = jhalf*2 + jt_local;
  const int row0 = b*NS + c*CHUNK;
  const int jrow0 = row0 + jhalf*32;

  {
    const int sb = wid * 64;
    {
      const int s = sb + lane;
      const int r = s >> 3, bk = s & 7;
      const size_t go = (size_t)(jrow0 + r)*512 + h*64 + bk*8;
      GLDS16(qh + go, qh_s + sb*8);
      GLDS16(ql + go, ql_s + sb*8);
    }
    #pragma unroll
    for (int i = 0; i < 2; ++i) {
      const int s = i*256 + sb + lane;
      const int r = s >> 3, bk = s & 7;
      const size_t go = (size_t)(row0 + r)*512 + h*64 + bk*8;
      GLDS16(kh + go, kh_s + (i*256 + sb)*8);
      GLDS16(kl + go, kl_s + (i*256 + sb)*8);
    }
    #pragma unroll
    for (int i = 0; i < 4; ++i) {
      const int s = i*256 + sb + lane;
      GLDS16(vT  + (size_t)task*8192 + s*8, vt_s + (i*256 + sb)*8);
      GLDS16(C0T + (size_t)task*8192 + s*8, c0_s + (i*256 + sb)*8);
    }
  }
  const float m0v = m0g[bh*NCHUNK + c];
  if (t < 64) {
    g_l[t]  = g_g[bh*NS + c*CHUNK + t];
    n0_l[t] = n0g[task*64 + t];
  } else if (t < 96) {
    int jl = t - 64;
    float av = a_g[bh*NS + c*CHUNK + jhalf*32 + jl];
    a_l[jl] = av;
    m_l[jl] = m_g[bh*NS + c*CHUNK + jhalf*32 + jl];
    cI_l[jl] = __expf(m0v - av);
  }
  __syncthreads();

  // ---- Phase A: QK^T (hi/lo), mask+exp, row sums, P->bf16
  float rsum[4] = {0.f, 0.f, 0.f, 0.f};
  for (int st = half; st < 4; st += 2) {
    if (st <= jtg) {
      f32x4 sacc = {};
      #pragma unroll
      for (int kk = 0; kk < 2; ++kk) {
        const int kg = kk*4 + lg;
        const int Ra = jt_local*16 + fr;
        const int Rb = st*16 + fr;
        bf16x8 qhv = *(const bf16x8*)&qh_s[Ra*64 + ((kg ^ (Ra&7))*8)];
        bf16x8 qlv = *(const bf16x8*)&ql_s[Ra*64 + ((kg ^ (Ra&7))*8)];
        bf16x8 khv = *(const bf16x8*)&kh_s[Rb*64 + ((kg ^ (Rb&7))*8)];
        bf16x8 klv = *(const bf16x8*)&kl_s[Rb*64 + ((kg ^ (Rb&7))*8)];
        sacc = __builtin_amdgcn_mfma_f32_16x16x32_bf16(qhv, khv, sacc, 0, 0, 0);
        sacc = __builtin_amdgcn_mfma_f32_16x16x32_bf16(qhv, klv, sacc, 0, 0, 0);
        sacc = __builtin_amdgcn_mfma_f32_16x16x32_bf16(qlv, khv, sacc, 0, 0, 0);
      }
      const int s_c = st*16 + fr;
      const float gs = g_l[s_c];
      #pragma unroll
      for (int r = 0; r < 4; ++r) {
        const int jl = jt_local*16 + lg*4 + r;
        const int j_c = jhalf*32 + jl;
        float w = (s_c <= j_c) ? __expf(gs - a_l[jl]) : 0.f;
        float p = sacc[r] * w;
        rsum[r] += p;
        Ps[jl*72 + s_c] = (__bf16)p;
      }
    } else {
      #pragma unroll
      for (int r = 0; r < 4; ++r)
        Ps[(jt_local*16 + lg*4 + r)*72 + st*16 + fr] = (__bf16)0.f;
    }
  }
  #pragma unroll
  for (int r = 0; r < 4; ++r) {
    #pragma unroll
    for (int off = 1; off < 16; off <<= 1) rsum[r] += __shfl_xor(rsum[r], off, 64);
  }
  if (fr == 0) {
    #pragma unroll
    for (int r = 0; r < 4; ++r) qnA[half][jt_local*16 + lg*4 + r] = rsum[r];
  }

  // ---- inter term: acc[j][u] = q_hi . C0T, then * cI[j]
  f32x4 acc[4] = {};
  #pragma unroll
  for (int kk = 0; kk < 2; ++kk) {
    const int kg = kk*4 + lg;
    const int Ra = jt_local*16 + fr;
    bf16x8 aq = *(const bf16x8*)&qh_s[Ra*64 + ((kg ^ (Ra&7))*8)];
    #pragma unroll
    for (int nt = 0; nt < 4; ++nt) {
      const int Rb = (half*4 + nt)*16 + fr;
      bf16x8 bc = *(const bf16x8*)&c0_s[Rb*64 + ((kg ^ (Rb&7))*8)];
      acc[nt] = __builtin_amdgcn_mfma_f32_16x16x32_bf16(aq, bc, acc[nt], 0, 0, 0);
    }
  }
  {
    float ci4[4];
    #pragma unroll
    for (int r = 0; r < 4; ++r) ci4[r] = cI_l[jt_local*16 + lg*4 + r];
    #pragma unroll
    for (int nt = 0; nt < 4; ++nt)
      #pragma unroll
      for (int r = 0; r < 4; ++r) acc[nt][r] *= ci4[r];
  }
  if (half == 1) {
    const int jl = jt_local*16 + fr;
    float s = 0.f;
    #pragma unroll
    for (int i = 0; i < 16; ++i) {
      const int d = lg*16 + i;
      const int off = jl*64 + (((d>>3) ^ (jl&7)) << 3) + (d & 7);
      float qv = (float)qh_s[off] + (float)ql_s[off];
      s += qv * n0_l[d];
    }
    s += __shfl_xor(s, 16, 64);
    s += __shfl_xor(s, 32, 64);
    if (lane < 16) qnI_l[jl] = cI_l[jl] * s;
  }
  __syncthreads();

  // ---- PV: acc += Ps . vT
  #pragma unroll
  for (int kk = 0; kk < 2; ++kk) {
    const int kg = kk*4 + lg;
    bf16x8 ap = *(const bf16x8*)&Ps[(jt_local*16 + fr)*72 + kg*8];
    #pragma unroll
    for (int nt = 0; nt < 4; ++nt) {
      const int Rb = (half*4 + nt)*16 + fr;
      bf16x8 bv = *(const bf16x8*)&vt_s[Rb*64 + ((kg ^ (Rb&7))*8)];
      acc[nt] = __builtin_amdgcn_mfma_f32_16x16x32_bf16(ap, bv, acc[nt], 0, 0, 0);
    }
  }

  // ---- epilogue part 1: denom + LN partials
  #pragma unroll
  for (int r = 0; r < 4; ++r) {
    const int jl = jt_local*16 + lg*4 + r;
    float qn = qnA[0][jl] + qnA[1][jl] + qnI_l[jl];
    float denom = fmaxf(fabsf(qn), __expf(-m_l[jl])) + 1e-6f;
    float rd = 1.f / denom;
    float s = 0.f, q2 = 0.f;
    #pragma unroll
    for (int nt = 0; nt < 4; ++nt) {
      float hv = acc[nt][r] * rd;
      acc[nt][r] = hv;
      s += hv; q2 += hv*hv;
    }
    #pragma unroll
    for (int off = 1; off < 16; off <<= 1) {
      s  += __shfl_xor(s,  off, 64);
      q2 += __shfl_xor(q2, off, 64);
    }
    if (fr == 0) { lnS[half][jl] = s; lnQ[half][jl] = q2; }
  }
  __syncthreads();

  // ---- epilogue part 2: LN + output gate + bf16 store
  #pragma unroll
  for (int r = 0; r < 4; ++r) {
    const int jl = jt_local*16 + lg*4 + r;
    float sm = lnS[0][jl] + lnS[1][jl];
    float sq = lnQ[0][jl] + lnQ[1][jl];
    float mu = sm * (1.f/128.f);
    float var = sq * (1.f/128.f) - mu*mu;
    float rstd = rsqrtf(var + 1e-6f);
    const int rowg = jrow0 + jl;
    #pragma unroll
    for (int nt = 0; nt < 4; ++nt) {
      const int u = (half*4 + nt)*16 + fr;
      float sg = (float)ogs[(size_t)rowg*1024 + h*DHV + u];
      float hn = (acc[nt][r] - mu) * rstd * gamma[h*DHV + u] * sg;
      hout[(size_t)rowg*NV + h*DHV + u] = (__bf16)hn;
    }
  }
}

extern "C" void kernel_launch(void* const* d_in, const int* in_sizes, int n_in,
                              void* d_out, int out_size, void* d_ws, size_t ws_size,
                              hipStream_t stream) {
  const float* x    = (const float*)d_in[0];
  const float* Wq   = (const float*)d_in[1];
  const float* Wk   = (const float*)d_in[2];
  const float* Wv   = (const float*)d_in[3];
  const float* Wog  = (const float*)d_in[4];
  const float* Wi   = (const float*)d_in[5];
  const float* bi   = (const float*)d_in[6];
  const float* Wf   = (const float*)d_in[7];
  const float* bf_  = (const float*)d_in[8];
  const float* gamma= (const float*)d_in[9];
  const float* Wout = (const float*)d_in[10];
  float* y = (float*)d_out;

  char* ws = (char*)d_ws;
  const size_t MB = 1u << 20;
  __bf16*   xb   = (__bf16*)  (ws + 0);        // 4 MB
  __bf16*   Wb   = (__bf16*)  (ws + 4*MB);     // 6 MB
  __bf16*   Wob  = (__bf16*)  (ws + 10*MB);    // 2 MB
  __bf16*   qh   = (__bf16*)  (ws + 12*MB);    // 2 MB  [2048][512] swz
  __bf16*   ql   = (__bf16*)  (ws + 14*MB);    // 2 MB
  __bf16*   kh   = (__bf16*)  (ws + 16*MB);    // 2 MB
  __bf16*   kl   = (__bf16*)  (ws + 18*MB);    // 2 MB
  __bf16*   kT   = (__bf16*)  (ws + 20*MB);    // 2 MB  [256][64][64] swz
  __bf16*   vT   = (__bf16*)  (ws + 22*MB);    // 4 MB  [256][128][64] swz
  _Float16* ogs  = (_Float16*)(ws + 26*MB);    // 4 MB  [2048][1024] sigmoid
  float*    Ut   = (float*)   (ws + 30*MB);    // 8 MB  [256][128][64]
  __bf16*   C0T  = (__bf16*)  (ws + 38*MB);    // 4 MB  [256][128][64] swz
  float*    icap = (float*)   (ws + 42*MB);
  float*    flog = (float*)   (ws + 42*MB + 64*1024);
  float*    g_g  = (float*)   (ws + 42*MB + 128*1024);
  float*    a_g  = (float*)   (ws + 42*MB + 192*1024);
  float*    m_g  = (float*)   (ws + 42*MB + 256*1024);
  float*    m0g  = (float*)   (ws + 42*MB + 320*1024);
  float*    Ung  = (float*)   (ws + 42*MB + 384*1024);
  float*    n0g  = (float*)   (ws + 42*MB + 448*1024);
  __bf16*   houtb= (__bf16*)  (ws + 44*MB);    // 4 MB

  cvt_all<<<6144, 256, 0, stream>>>(x, Wq, Wk, Wv, Wog, Wout, xb, Wb, Wob);

  gemm_proj<<<384, 256, 0, stream>>>(xb, Wb, qh, ql, kh, kl, kT, vT, ogs);

  ifgate_kernel<<<2048, 256, 0, stream>>>(x, Wi, bi, Wf, bf_, icap, flog);
  gates_kernel<<<16, 64, 0, stream>>>(icap, flog, g_g, a_g, m_g, m0g);
  u_kernel<<<256, 256, 0, stream>>>(kT, vT, g_g, a_g, Ut, Ung);
  statescan_kernel<<<256, 64, 0, stream>>>(Ut, Ung, m0g, a_g, C0T, n0g);
  intra_kernel<<<512, 256, 0, stream>>>(qh, ql, kh, kl, vT, C0T, ogs,
                                        g_g, a_g, m_g, m0g, n0g, gamma, houtb);

  gemm_bt<<<128, 256, 0, stream>>>(houtb, Wob, y, 2048, 1024, 1024, 8, 128);
}

// Round 8
// 171.429 us; speedup vs baseline: 1.0691x; 1.0691x over previous
//
#include <hip/hip_runtime.h>
#include <hip/hip_bf16.h>
#include <math.h>

typedef __bf16 bf16x8 __attribute__((ext_vector_type(8)));
typedef float f32x4 __attribute__((ext_vector_type(4)));

#define NB 2
#define NS 1024
#define ND 1024
#define NH 8
#define NQK 512
#define NV 1024
#define DQK 64
#define DHV 128
#define CHUNK 64
#define NCHUNK 16

#define GLDS16(g, l) __builtin_amdgcn_global_load_lds((const __attribute__((address_space(1))) void*)(g), (__attribute__((address_space(3))) void*)(l), 16, 0, 0)

static __device__ __forceinline__ void split_bf16(float v, __bf16& hi, __bf16& lo) {
  hi = (__bf16)v;
  lo = (__bf16)(v - (float)hi);
}

// bijective XCD swizzle (m204)
static __device__ __forceinline__ int xcd_swz(int orig, int nwg) {
  int q = nwg >> 3, r = nwg & 7;
  int xcd = orig & 7, idx = orig >> 3;
  int base = (xcd < r) ? xcd * (q + 1) : r * (q + 1) + (xcd - r) * q;
  return base + idx;
}

// ---------------- fused f32 -> bf16 conversion (all 6 tensors, 1 launch) ----------------
__global__ __launch_bounds__(256) void cvt_all(const float* __restrict__ x,
    const float* __restrict__ wq, const float* __restrict__ wk,
    const float* __restrict__ wv, const float* __restrict__ wog,
    const float* __restrict__ wout,
    __bf16* __restrict__ xb, __bf16* __restrict__ wb, __bf16* __restrict__ wob) {
  long i = (long)blockIdx.x * 256 + threadIdx.x;   // float4 index
  const float* src; __bf16* dst;
  if (i < 524288)        { src = x    + i*4;                    dst = xb  + i*4; }
  else if (i < 655360)   { long j = i -  524288; src = wq  + j*4; dst = wb + j*4; }
  else if (i < 786432)   { long j = i -  655360; src = wk  + j*4; dst = wb +  524288 + j*4; }
  else if (i < 1048576)  { long j = i -  786432; src = wv  + j*4; dst = wb + 1048576 + j*4; }
  else if (i < 1310720)  { long j = i - 1048576; src = wog + j*4; dst = wb + 2097152 + j*4; }
  else                   { long j = i - 1310720; src = wout+ j*4; dst = wob + j*4; }
  float4 v = *(const float4*)src;
  __bf16 o[4];
  o[0] = (__bf16)v.x; o[1] = (__bf16)v.y; o[2] = (__bf16)v.z; o[3] = (__bf16)v.w;
  *(short4*)dst = *(const short4*)o;
}

// ---------------- shared staging: A = 128 rows (1024 slots), B = 64 rows (512 slots) ----------------
#define STAGE_AB(Abuf, Bbuf, Aptr, Bptr, Krun, ktv)                           \
  do {                                                                        \
    _Pragma("unroll")                                                         \
    for (int i_ = 0; i_ < 4; ++i_) {                                          \
      const int sb_ = i_ * 256 + wid * 64;                                    \
      const int s_ = sb_ + lane;                                              \
      const int row_ = s_ >> 3;                                               \
      const int klog_ = (s_ & 7) ^ (row_ & 7);                                \
      GLDS16(Aptr + (size_t)(m0 + row_) * Krun + (ktv) * 64 + klog_ * 8, Abuf + sb_ * 8); \
      if (i_ < 2)                                                             \
        GLDS16(Bptr + (size_t)(n0 + row_) * Krun + (ktv) * 64 + klog_ * 8, Bbuf + sb_ * 8); \
    }                                                                         \
  } while (0)

// ---------------- generic bf16 GEMM, C[M,N] = A[M,K]*B[N,K]^T, f32 out ----------------
// 128x64 tile, 4 waves (wave tile 64x32), BK=64 dbuf, source-swizzled LDS, XCD swizzle.
__global__ __launch_bounds__(256) void gemm_bt(const __bf16* __restrict__ A,
                                               const __bf16* __restrict__ Bm,
                                               float* __restrict__ C,
                                               int M, int N, int K, int ntn, int nwg) {
  __shared__ __bf16 smA[2][128 * 64];
  __shared__ __bf16 smB[2][64 * 64];
  const int wg = xcd_swz(blockIdx.x, nwg);
  const int m0 = (wg / ntn) * 128;
  const int n0 = (wg % ntn) * 64;
  const int tid = threadIdx.x;
  const int wid = tid >> 6, lane = tid & 63;
  const int wm = (wid >> 1) * 64, wn = (wid & 1) * 32;
  const int fr = lane & 15;
  const int g  = lane >> 4;
  f32x4 acc[4][2] = {};
  const int NT = K >> 6;
  STAGE_AB(smA[0], smB[0], A, Bm, K, 0);
  int cur = 0;
  for (int kt = 0; kt < NT; ++kt) {
    __syncthreads();
    if (kt + 1 < NT) STAGE_AB(smA[cur ^ 1], smB[cur ^ 1], A, Bm, K, kt + 1);
    #pragma unroll
    for (int kk = 0; kk < 2; ++kk) {
      const int kg = kk * 4 + g;
      bf16x8 af[4], bfv[2];
      #pragma unroll
      for (int f = 0; f < 4; ++f) {
        const int Ra = wm + f * 16 + fr;
        af[f] = *(const bf16x8*)&smA[cur][Ra * 64 + ((kg ^ (Ra & 7)) * 8)];
      }
      #pragma unroll
      for (int n = 0; n < 2; ++n) {
        const int Rb = wn + n * 16 + fr;
        bfv[n] = *(const bf16x8*)&smB[cur][Rb * 64 + ((kg ^ (Rb & 7)) * 8)];
      }
      #pragma unroll
      for (int i = 0; i < 4; ++i)
        #pragma unroll
        for (int j = 0; j < 2; ++j)
          acc[i][j] = __builtin_amdgcn_mfma_f32_16x16x32_bf16(af[i], bfv[j], acc[i][j], 0, 0, 0);
    }
    cur ^= 1;
  }
  const int orow = m0 + wm + g * 4;
  const int ocol = n0 + wn + fr;
  #pragma unroll
  for (int i = 0; i < 4; ++i)
    #pragma unroll
    for (int j = 0; j < 2; ++j)
      #pragma unroll
      for (int r = 0; r < 4; ++r)
        C[(size_t)(orow + i*16 + r) * N + (ocol + j*16)] = acc[i][j][r];
}

// ---------------- projection GEMM with format-aware epilogue ----------------
// cols 0-511 -> q (x0.125 hi/lo, swz), 512-1023 -> k (hi/lo swz + kT tiles),
// 1024-2047 -> vT tiles, 2048-3071 -> sigmoid f16. Direct stores (round-4 form).
__global__ __launch_bounds__(256) void gemm_proj(const __bf16* __restrict__ A,
    const __bf16* __restrict__ Bm,
    __bf16* __restrict__ qh, __bf16* __restrict__ ql,
    __bf16* __restrict__ kh, __bf16* __restrict__ kl,
    __bf16* __restrict__ kT, __bf16* __restrict__ vT,
    _Float16* __restrict__ ogs) {
  __shared__ __bf16 smA[2][128 * 64];
  __shared__ __bf16 smB[2][64 * 64];
  const int wg = xcd_swz(blockIdx.x, 768);
  const int m0 = (wg / 48) * 128;
  const int n0 = (wg % 48) * 64;
  const int tid = threadIdx.x;
  const int wid = tid >> 6, lane = tid & 63;
  const int wm = (wid >> 1) * 64, wn = (wid & 1) * 32;
  const int fr = lane & 15;
  const int g  = lane >> 4;
  f32x4 acc[4][2] = {};
  STAGE_AB(smA[0], smB[0], A, Bm, 1024, 0);
  int cur = 0;
  for (int kt = 0; kt < 16; ++kt) {
    __syncthreads();
    if (kt + 1 < 16) STAGE_AB(smA[cur ^ 1], smB[cur ^ 1], A, Bm, 1024, kt + 1);
    #pragma unroll
    for (int kk = 0; kk < 2; ++kk) {
      const int kg = kk * 4 + g;
      bf16x8 af[4], bfv[2];
      #pragma unroll
      for (int f = 0; f < 4; ++f) {
        const int Ra = wm + f * 16 + fr;
        af[f] = *(const bf16x8*)&smA[cur][Ra * 64 + ((kg ^ (Ra & 7)) * 8)];
      }
      #pragma unroll
      for (int n = 0; n < 2; ++n) {
        const int Rb = wn + n * 16 + fr;
        bfv[n] = *(const bf16x8*)&smB[cur][Rb * 64 + ((kg ^ (Rb & 7)) * 8)];
      }
      #pragma unroll
      for (int i = 0; i < 4; ++i)
        #pragma unroll
        for (int j = 0; j < 2; ++j)
          acc[i][j] = __builtin_amdgcn_mfma_f32_16x16x32_bf16(af[i], bfv[j], acc[i][j], 0, 0, 0);
    }
    cur ^= 1;
  }
  const int orow = m0 + wm + g * 4;
  const int ocol = n0 + wn + fr;
  const int rng = n0 >> 9;   // 0: q, 1: k, 2..3: v, 4..5: og
  if (rng == 0 || rng == 1) {
    __bf16* Hb = (rng == 0) ? qh : kh;
    __bf16* Lb = (rng == 0) ? ql : kl;
    const float sc = (rng == 0) ? 0.125f : 1.0f;
    #pragma unroll
    for (int i = 0; i < 4; ++i)
      #pragma unroll
      for (int j = 0; j < 2; ++j) {
        const int col = (ocol + j*16) & 511;      // within tensor
        const int d = col & 63;
        const int hb = col & ~63;
        __bf16 t4[4];
        #pragma unroll
        for (int r = 0; r < 4; ++r) {
          const int row = orow + i*16 + r;
          float v = acc[i][j][r] * sc;
          __bf16 hi, lo; split_bf16(v, hi, lo);
          t4[r] = hi;
          const int off = row*512 + hb + ((((d>>3) ^ (row&7))) << 3) + (d & 7);
          Hb[off] = hi;
          Lb[off] = lo;
        }
        if (rng == 1) {
          const int row0r = orow + i*16;
          const int bh = ((row0r >> 10) << 3) + (col >> 6);
          const int c = (row0r >> 6) & 15;
          const int s0 = (row0r & 63);
          const int off = ((bh*16 + c)*64 + d)*64 + (((s0>>3) ^ (d&7)) << 3) + (s0 & 7);
          *(short4*)&kT[off] = *(const short4*)t4;
        }
      }
  } else if (rng == 2 || rng == 3) {
    #pragma unroll
    for (int i = 0; i < 4; ++i)
      #pragma unroll
      for (int j = 0; j < 2; ++j) {
        const int col = (ocol + j*16) & 1023;
        const int u = col & 127;
        __bf16 t4[4];
        #pragma unroll
        for (int r = 0; r < 4; ++r) t4[r] = (__bf16)acc[i][j][r];
        const int row0r = orow + i*16;
        const int bh = ((row0r >> 10) << 3) + (col >> 7);
        const int c = (row0r >> 6) & 15;
        const int s0 = (row0r & 63);
        const int off = ((bh*16 + c)*128 + u)*64 + (((s0>>3) ^ (u&7)) << 3) + (s0 & 7);
        *(short4*)&vT[off] = *(const short4*)t4;
      }
  } else {
    #pragma unroll
    for (int i = 0; i < 4; ++i)
      #pragma unroll
      for (int j = 0; j < 2; ++j) {
        const int col = (ocol + j*16) & 1023;
        #pragma unroll
        for (int r = 0; r < 4; ++r) {
          const int row = orow + i*16 + r;
          float sg = 1.f / (1.f + __expf(-acc[i][j][r]));
          ogs[(size_t)row*1024 + col] = (_Float16)sg;
        }
      }
  }
}

// ---------------- i/f gate pre-activations (full f32) ----------------
__global__ __launch_bounds__(256) void ifgate_kernel(const float* __restrict__ x,
    const float* __restrict__ Wi, const float* __restrict__ bi,
    const float* __restrict__ Wf, const float* __restrict__ bf_,
    float* __restrict__ icap, float* __restrict__ flog) {
  const int row = blockIdx.x;
  const int w = threadIdx.x >> 6;
  const int l = threadIdx.x & 63;
  const float* xr = x + (size_t)row * ND;
  float xv[16];
  #pragma unroll
  for (int t = 0; t < 16; ++t) xv[t] = xr[l + 64*t];
  for (int hh = 0; hh < 2; ++hh) {
    int h = w*2 + hh;
    const float* wi = Wi + (size_t)h * ND;
    const float* wf = Wf + (size_t)h * ND;
    float si = 0.f, sf = 0.f;
    #pragma unroll
    for (int t = 0; t < 16; ++t) {
      si += xv[t] * wi[l + 64*t];
      sf += xv[t] * wf[l + 64*t];
    }
    #pragma unroll
    for (int off = 32; off; off >>= 1) {
      si += __shfl_xor(si, off, 64);
      sf += __shfl_xor(sf, off, 64);
    }
    if (l == 0) {
      float ic = 15.f * tanhf((si + bi[h]) * (1.f/15.f));
      float fc = 15.f * tanhf((sf + bf_[h]) * (1.f/15.f));
      float fl = (fc >= 0.f) ? -log1pf(__expf(-fc)) : (fc - log1pf(__expf(fc)));
      icap[row*NH + h] = ic;
      flog[row*NH + h] = fl;
    }
  }
}

// ---------------- gate scan: per (b,h), chunked cumsum/cummax ----------------
__global__ __launch_bounds__(64) void gates_kernel(const float* __restrict__ icap,
    const float* __restrict__ flog, float* __restrict__ g_g, float* __restrict__ a_g,
    float* __restrict__ m_g, float* __restrict__ m0g) {
  const int bh = blockIdx.x;
  const int b = bh >> 3, h = bh & 7;
  const int l = threadIdx.x;
  float m0 = 0.f;
  for (int c = 0; c < NCHUNK; ++c) {
    const int t = c*CHUNK + l;
    const int row = b*NS + t;
    float B = flog[row*NH + h];
    float iv = icap[row*NH + h];
    #pragma unroll
    for (int d = 1; d < 64; d <<= 1) {
      float o = __shfl_up(B, d, 64);
      if (l >= d) B += o;
    }
    float g = iv - B;
    float cm = g;
    #pragma unroll
    for (int d = 1; d < 64; d <<= 1) {
      float o = __shfl_up(cm, d, 64);
      if (l >= d) cm = fmaxf(cm, o);
    }
    float a = fmaxf(m0, cm);
    float m = B + a;
    const int idx = bh*NS + t;
    g_g[idx] = g; a_g[idx] = a; m_g[idx] = m;
    if (l == 0) m0g[bh*NCHUNK + c] = m0;
    m0 = __shfl(m, 63, 64);
  }
}

// ---------------- per-chunk U^T[u][d] = sum_s v[s][u] (w_s k[s][d]) via MFMA ----------------
__global__ __launch_bounds__(256) void u_kernel(const __bf16* __restrict__ kT,
    const __bf16* __restrict__ vT, const float* __restrict__ g_g,
    const float* __restrict__ a_g, float* __restrict__ Ut, float* __restrict__ Ung) {
  __shared__ __bf16 kts[64 * 64];
  __shared__ __bf16 vts[128 * 64];
  __shared__ float w_l[64];
  const int task = blockIdx.x;
  const int bh = task >> 4, c = task & 15;
  const int t = threadIdx.x;
  const int wid = t >> 6, lane = t & 63;
  const int fr = lane & 15, g = lane >> 4;
  if (t < 64) {
    const float aL = a_g[bh*NS + c*CHUNK + 63];
    w_l[t] = __expf(g_g[bh*NS + c*CHUNK + t] - aL);
  }
  {
    const int sb = wid * 64;
    #pragma unroll
    for (int i = 0; i < 2; ++i) {
      const int s = i*256 + sb + lane;
      GLDS16(kT + (size_t)task*4096 + s*8, kts + (i*256 + sb)*8);
    }
    #pragma unroll
    for (int i = 0; i < 4; ++i) {
      const int s = i*256 + sb + lane;
      GLDS16(vT + (size_t)task*8192 + s*8, vts + (i*256 + sb)*8);
    }
  }
  __syncthreads();
  f32x4 acc[8] = {};
  #pragma unroll
  for (int kk = 0; kk < 2; ++kk) {
    const int kg = kk*4 + g;
    const int Ra = wid*16 + fr;
    bf16x8 afr = *(const bf16x8*)&kts[Ra*64 + ((kg ^ (Ra & 7)) * 8)];
    bf16x8 afw;
    #pragma unroll
    for (int j = 0; j < 8; ++j) afw[j] = (__bf16)((float)afr[j] * w_l[kg*8 + j]);
    #pragma unroll
    for (int nt = 0; nt < 8; ++nt) {
      const int Rb = nt*16 + fr;
      bf16x8 bv = *(const bf16x8*)&vts[Rb*64 + ((kg ^ (Rb & 7)) * 8)];
      acc[nt] = __builtin_amdgcn_mfma_f32_16x16x32_bf16(afw, bv, acc[nt], 0, 0, 0);
    }
  }
  float* ub = Ut + (size_t)task * 8192;
  #pragma unroll
  for (int nt = 0; nt < 8; ++nt) {
    const int u = nt*16 + fr;
    *(f32x4*)&ub[u*64 + wid*16 + g*4] = acc[nt];
  }
  if (t < 64) {
    float s = 0.f;
    #pragma unroll
    for (int blk = 0; blk < 8; ++blk) {
      bf16x8 kv = *(const bf16x8*)&kts[t*64 + ((blk ^ (t & 7)) * 8)];
      #pragma unroll
      for (int j = 0; j < 8; ++j) s += (float)kv[j] * w_l[blk*8 + j];
    }
    Ung[task*64 + t] = s;
  }
}

// ---------------- inter-chunk state prefix scan (spread across all CUs) ----------------
__global__ __launch_bounds__(64) void statescan_kernel(const float* __restrict__ Ut,
    const float* __restrict__ Ung, const float* __restrict__ m0g,
    const float* __restrict__ a_g, __bf16* __restrict__ C0T, float* __restrict__ n0g) {
  const int bh = blockIdx.x >> 4, part = blockIdx.x & 15;
  const int e8 = part*64 + threadIdx.x;      // 0..1023: group of 8 d for one u
  const int u = e8 >> 3, d8 = e8 & 7;
  const int dsto = u*64 + ((d8 ^ (u & 7)) << 3);
  const int srco = u*64 + d8*8;
  float scale[NCHUNK];
  #pragma unroll
  for (int c = 0; c < NCHUNK; ++c)
    scale[c] = __expf(m0g[bh*NCHUNK + c] - a_g[bh*NS + c*CHUNK + 63]);
  float val[8] = {};
  for (int c = 0; c < NCHUNK; ++c) {
    const size_t base = ((size_t)(bh*NCHUNK + c)) * 8192;
    __bf16 o[8];
    #pragma unroll
    for (int j = 0; j < 8; ++j) o[j] = (__bf16)val[j];
    *(float4*)&C0T[base + dsto] = *(const float4*)o;
    f32x4 u0 = *(const f32x4*)&Ut[base + srco];
    f32x4 u1 = *(const f32x4*)&Ut[base + srco + 4];
    #pragma unroll
    for (int j = 0; j < 4; ++j) {
      val[j]   = scale[c]*val[j]   + u0[j];
      val[j+4] = scale[c]*val[j+4] + u1[j];
    }
  }
  if (part == 0) {
    float nv = 0.f;
    for (int c = 0; c < NCHUNK; ++c) {
      int idx = (bh*NCHUNK + c)*64 + threadIdx.x;
      n0g[idx] = nv;
      nv = scale[c]*nv + Ung[idx];
    }
  }
}

// ---------------- intra-chunk attention + inter + denom + LN + gate (MFMA, GLDS-staged) ----------------
__global__ __launch_bounds__(256) void intra_kernel(
    const __bf16* __restrict__ qh, const __bf16* __restrict__ ql,
    const __bf16* __restrict__ kh, const __bf16* __restrict__ kl,
    const __bf16* __restrict__ vT, const __bf16* __restrict__ C0T,
    const _Float16* __restrict__ ogs,
    const float* __restrict__ g_g, const float* __restrict__ a_g,
    const float* __restrict__ m_g, const float* __restrict__ m0g,
    const float* __restrict__ n0g,
    const float* __restrict__ gamma, __bf16* __restrict__ hout) {
  __shared__ __bf16 qh_s[32*64], ql_s[32*64];
  __shared__ __bf16 kh_s[64*64], kl_s[64*64];
  __shared__ __bf16 vt_s[128*64];
  __shared__ __bf16 c0_s[128*64];
  __shared__ __bf16 Ps[32*72];
  __shared__ float g_l[64], n0_l[64], a_l[32], m_l[32], cI_l[32];
  __shared__ float qnA[2][32], qnI_l[32], lnS[2][32], lnQ[2][32];

  const int blk = blockIdx.x;
  const int task = blk >> 1, jhalf = blk & 1;
  const int bh = task >> 4, c = task & 15;
  const int b = bh >> 3, h = bh & 7;
  const int t = threadIdx.x;
  const int wid = t >> 6, lane = t & 63;
  const int fr = lane & 15, lg = lane >> 4;
  const int jt_local = wid >> 1, half = wid & 1;
  const int jtg = jhalf*2 + jt_local;
  const int row0 = b*NS + c*CHUNK;
  const int jrow0 = row0 + jhalf*32;

  {
    const int sb = wid * 64;
    {
      const int s = sb + lane;
      const int r = s >> 3, bk = s & 7;
      const size_t go = (size_t)(jrow0 + r)*512 + h*64 + bk*8;
      GLDS16(qh + go, qh_s + sb*8);
      GLDS16(ql + go, ql_s + sb*8);
    }
    #pragma unroll
    for (int i = 0; i < 2; ++i) {
      const int s = i*256 + sb + lane;
      const int r = s >> 3, bk = s & 7;
      const size_t go = (size_t)(row0 + r)*512 + h*64 + bk*8;
      GLDS16(kh + go, kh_s + (i*256 + sb)*8);
      GLDS16(kl + go, kl_s + (i*256 + sb)*8);
    }
    #pragma unroll
    for (int i = 0; i < 4; ++i) {
      const int s = i*256 + sb + lane;
      GLDS16(vT  + (size_t)task*8192 + s*8, vt_s + (i*256 + sb)*8);
      GLDS16(C0T + (size_t)task*8192 + s*8, c0_s + (i*256 + sb)*8);
    }
  }
  const float m0v = m0g[bh*NCHUNK + c];
  if (t < 64) {
    g_l[t]  = g_g[bh*NS + c*CHUNK + t];
    n0_l[t] = n0g[task*64 + t];
  } else if (t < 96) {
    int jl = t - 64;
    float av = a_g[bh*NS + c*CHUNK + jhalf*32 + jl];
    a_l[jl] = av;
    m_l[jl] = m_g[bh*NS + c*CHUNK + jhalf*32 + jl];
    cI_l[jl] = __expf(m0v - av);
  }
  __syncthreads();

  // ---- Phase A: QK^T (hi/lo), mask+exp, row sums, P->bf16
  float rsum[4] = {0.f, 0.f, 0.f, 0.f};
  for (int st = half; st < 4; st += 2) {
    if (st <= jtg) {
      f32x4 sacc = {};
      #pragma unroll
      for (int kk = 0; kk < 2; ++kk) {
        const int kg = kk*4 + lg;
        const int Ra = jt_local*16 + fr;
        const int Rb = st*16 + fr;
        bf16x8 qhv = *(const bf16x8*)&qh_s[Ra*64 + ((kg ^ (Ra&7))*8)];
        bf16x8 qlv = *(const bf16x8*)&ql_s[Ra*64 + ((kg ^ (Ra&7))*8)];
        bf16x8 khv = *(const bf16x8*)&kh_s[Rb*64 + ((kg ^ (Rb&7))*8)];
        bf16x8 klv = *(const bf16x8*)&kl_s[Rb*64 + ((kg ^ (Rb&7))*8)];
        sacc = __builtin_amdgcn_mfma_f32_16x16x32_bf16(qhv, khv, sacc, 0, 0, 0);
        sacc = __builtin_amdgcn_mfma_f32_16x16x32_bf16(qhv, klv, sacc, 0, 0, 0);
        sacc = __builtin_amdgcn_mfma_f32_16x16x32_bf16(qlv, khv, sacc, 0, 0, 0);
      }
      const int s_c = st*16 + fr;
      const float gs = g_l[s_c];
      #pragma unroll
      for (int r = 0; r < 4; ++r) {
        const int jl = jt_local*16 + lg*4 + r;
        const int j_c = jhalf*32 + jl;
        float w = (s_c <= j_c) ? __expf(gs - a_l[jl]) : 0.f;
        float p = sacc[r] * w;
        rsum[r] += p;
        Ps[jl*72 + s_c] = (__bf16)p;
      }
    } else {
      #pragma unroll
      for (int r = 0; r < 4; ++r)
        Ps[(jt_local*16 + lg*4 + r)*72 + st*16 + fr] = (__bf16)0.f;
    }
  }
  #pragma unroll
  for (int r = 0; r < 4; ++r) {
    #pragma unroll
    for (int off = 1; off < 16; off <<= 1) rsum[r] += __shfl_xor(rsum[r], off, 64);
  }
  if (fr == 0) {
    #pragma unroll
    for (int r = 0; r < 4; ++r) qnA[half][jt_local*16 + lg*4 + r] = rsum[r];
  }

  // ---- inter term: acc[j][u] = q_hi . C0T, then * cI[j]
  f32x4 acc[4] = {};
  #pragma unroll
  for (int kk = 0; kk < 2; ++kk) {
    const int kg = kk*4 + lg;
    const int Ra = jt_local*16 + fr;
    bf16x8 aq = *(const bf16x8*)&qh_s[Ra*64 + ((kg ^ (Ra&7))*8)];
    #pragma unroll
    for (int nt = 0; nt < 4; ++nt) {
      const int Rb = (half*4 + nt)*16 + fr;
      bf16x8 bc = *(const bf16x8*)&c0_s[Rb*64 + ((kg ^ (Rb&7))*8)];
      acc[nt] = __builtin_amdgcn_mfma_f32_16x16x32_bf16(aq, bc, acc[nt], 0, 0, 0);
    }
  }
  {
    float ci4[4];
    #pragma unroll
    for (int r = 0; r < 4; ++r) ci4[r] = cI_l[jt_local*16 + lg*4 + r];
    #pragma unroll
    for (int nt = 0; nt < 4; ++nt)
      #pragma unroll
      for (int r = 0; r < 4; ++r) acc[nt][r] *= ci4[r];
  }
  if (half == 1) {
    const int jl = jt_local*16 + fr;
    float s = 0.f;
    #pragma unroll
    for (int i = 0; i < 16; ++i) {
      const int d = lg*16 + i;
      const int off = jl*64 + (((d>>3) ^ (jl&7)) << 3) + (d & 7);
      float qv = (float)qh_s[off] + (float)ql_s[off];
      s += qv * n0_l[d];
    }
    s += __shfl_xor(s, 16, 64);
    s += __shfl_xor(s, 32, 64);
    if (lane < 16) qnI_l[jl] = cI_l[jl] * s;
  }
  __syncthreads();

  // ---- PV: acc += Ps . vT
  #pragma unroll
  for (int kk = 0; kk < 2; ++kk) {
    const int kg = kk*4 + lg;
    bf16x8 ap = *(const bf16x8*)&Ps[(jt_local*16 + fr)*72 + kg*8];
    #pragma unroll
    for (int nt = 0; nt < 4; ++nt) {
      const int Rb = (half*4 + nt)*16 + fr;
      bf16x8 bv = *(const bf16x8*)&vt_s[Rb*64 + ((kg ^ (Rb&7))*8)];
      acc[nt] = __builtin_amdgcn_mfma_f32_16x16x32_bf16(ap, bv, acc[nt], 0, 0, 0);
    }
  }

  // ---- epilogue part 1: denom + LN partials
  #pragma unroll
  for (int r = 0; r < 4; ++r) {
    const int jl = jt_local*16 + lg*4 + r;
    float qn = qnA[0][jl] + qnA[1][jl] + qnI_l[jl];
    float denom = fmaxf(fabsf(qn), __expf(-m_l[jl])) + 1e-6f;
    float rd = 1.f / denom;
    float s = 0.f, q2 = 0.f;
    #pragma unroll
    for (int nt = 0; nt < 4; ++nt) {
      float hv = acc[nt][r] * rd;
      acc[nt][r] = hv;
      s += hv; q2 += hv*hv;
    }
    #pragma unroll
    for (int off = 1; off < 16; off <<= 1) {
      s  += __shfl_xor(s,  off, 64);
      q2 += __shfl_xor(q2, off, 64);
    }
    if (fr == 0) { lnS[half][jl] = s; lnQ[half][jl] = q2; }
  }
  __syncthreads();

  // ---- epilogue part 2: LN + output gate + bf16 store
  #pragma unroll
  for (int r = 0; r < 4; ++r) {
    const int jl = jt_local*16 + lg*4 + r;
    float sm = lnS[0][jl] + lnS[1][jl];
    float sq = lnQ[0][jl] + lnQ[1][jl];
    float mu = sm * (1.f/128.f);
    float var = sq * (1.f/128.f) - mu*mu;
    float rstd = rsqrtf(var + 1e-6f);
    const int rowg = jrow0 + jl;
    #pragma unroll
    for (int nt = 0; nt < 4; ++nt) {
      const int u = (half*4 + nt)*16 + fr;
      float sg = (float)ogs[(size_t)rowg*1024 + h*DHV + u];
      float hn = (acc[nt][r] - mu) * rstd * gamma[h*DHV + u] * sg;
      hout[(size_t)rowg*NV + h*DHV + u] = (__bf16)hn;
    }
  }
}

extern "C" void kernel_launch(void* const* d_in, const int* in_sizes, int n_in,
                              void* d_out, int out_size, void* d_ws, size_t ws_size,
                              hipStream_t stream) {
  const float* x    = (const float*)d_in[0];
  const float* Wq   = (const float*)d_in[1];
  const float* Wk   = (const float*)d_in[2];
  const float* Wv   = (const float*)d_in[3];
  const float* Wog  = (const float*)d_in[4];
  const float* Wi   = (const float*)d_in[5];
  const float* bi   = (const float*)d_in[6];
  const float* Wf   = (const float*)d_in[7];
  const float* bf_  = (const float*)d_in[8];
  const float* gamma= (const float*)d_in[9];
  const float* Wout = (const float*)d_in[10];
  float* y = (float*)d_out;

  char* ws = (char*)d_ws;
  const size_t MB = 1u << 20;
  __bf16*   xb   = (__bf16*)  (ws + 0);        // 4 MB
  __bf16*   Wb   = (__bf16*)  (ws + 4*MB);     // 6 MB
  __bf16*   Wob  = (__bf16*)  (ws + 10*MB);    // 2 MB
  __bf16*   qh   = (__bf16*)  (ws + 12*MB);    // 2 MB  [2048][512] swz
  __bf16*   ql   = (__bf16*)  (ws + 14*MB);    // 2 MB
  __bf16*   kh   = (__bf16*)  (ws + 16*MB);    // 2 MB
  __bf16*   kl   = (__bf16*)  (ws + 18*MB);    // 2 MB
  __bf16*   kT   = (__bf16*)  (ws + 20*MB);    // 2 MB  [256][64][64] swz
  __bf16*   vT   = (__bf16*)  (ws + 22*MB);    // 4 MB  [256][128][64] swz
  _Float16* ogs  = (_Float16*)(ws + 26*MB);    // 4 MB  [2048][1024] sigmoid
  float*    Ut   = (float*)   (ws + 30*MB);    // 8 MB  [256][128][64]
  __bf16*   C0T  = (__bf16*)  (ws + 38*MB);    // 4 MB  [256][128][64] swz
  float*    icap = (float*)   (ws + 42*MB);
  float*    flog = (float*)   (ws + 42*MB + 64*1024);
  float*    g_g  = (float*)   (ws + 42*MB + 128*1024);
  float*    a_g  = (float*)   (ws + 42*MB + 192*1024);
  float*    m_g  = (float*)   (ws + 42*MB + 256*1024);
  float*    m0g  = (float*)   (ws + 42*MB + 320*1024);
  float*    Ung  = (float*)   (ws + 42*MB + 384*1024);
  float*    n0g  = (float*)   (ws + 42*MB + 448*1024);
  __bf16*   houtb= (__bf16*)  (ws + 44*MB);    // 4 MB

  cvt_all<<<6144, 256, 0, stream>>>(x, Wq, Wk, Wv, Wog, Wout, xb, Wb, Wob);

  gemm_proj<<<768, 256, 0, stream>>>(xb, Wb, qh, ql, kh, kl, kT, vT, ogs);

  ifgate_kernel<<<2048, 256, 0, stream>>>(x, Wi, bi, Wf, bf_, icap, flog);
  gates_kernel<<<16, 64, 0, stream>>>(icap, flog, g_g, a_g, m_g, m0g);
  u_kernel<<<256, 256, 0, stream>>>(kT, vT, g_g, a_g, Ut, Ung);
  statescan_kernel<<<256, 64, 0, stream>>>(Ut, Ung, m0g, a_g, C0T, n0g);
  intra_kernel<<<512, 256, 0, stream>>>(qh, ql, kh, kl, vT, C0T, ogs,
                                        g_g, a_g, m_g, m0g, n0g, gamma, houtb);

  gemm_bt<<<256, 256, 0, stream>>>(houtb, Wob, y, 2048, 1024, 1024, 16, 256);
}

// Round 9
// 163.432 us; speedup vs baseline: 1.1214x; 1.0489x over previous
//
#include <hip/hip_runtime.h>
#include <hip/hip_bf16.h>
#include <math.h>

typedef __bf16 bf16x8 __attribute__((ext_vector_type(8)));
typedef float f32x4 __attribute__((ext_vector_type(4)));

#define NB 2
#define NS 1024
#define ND 1024
#define NH 8
#define NQK 512
#define NV 1024
#define DQK 64
#define DHV 128
#define CHUNK 64
#define NCHUNK 16

#define GLDS16(g, l) __builtin_amdgcn_global_load_lds((const __attribute__((address_space(1))) void*)(g), (__attribute__((address_space(3))) void*)(l), 16, 0, 0)

static __device__ __forceinline__ void split_bf16(float v, __bf16& hi, __bf16& lo) {
  hi = (__bf16)v;
  lo = (__bf16)(v - (float)hi);
}

// bijective XCD swizzle (m204)
static __device__ __forceinline__ int xcd_swz(int orig, int nwg) {
  int q = nwg >> 3, r = nwg & 7;
  int xcd = orig & 7, idx = orig >> 3;
  int base = (xcd < r) ? xcd * (q + 1) : r * (q + 1) + (xcd - r) * q;
  return base + idx;
}

// ---------------- fused prep: f32->bf16 cvt (blocks 0..6143) + i/f gates (6144..8191) ----------------
__global__ __launch_bounds__(256) void prep_kernel(const float* __restrict__ x,
    const float* __restrict__ wq, const float* __restrict__ wk,
    const float* __restrict__ wv, const float* __restrict__ wog,
    const float* __restrict__ wout,
    const float* __restrict__ Wi, const float* __restrict__ bi,
    const float* __restrict__ Wf, const float* __restrict__ bf_,
    __bf16* __restrict__ xb, __bf16* __restrict__ wb, __bf16* __restrict__ wob,
    float* __restrict__ icap, float* __restrict__ flog) {
  if (blockIdx.x < 6144) {
    long i = (long)blockIdx.x * 256 + threadIdx.x;   // float4 index
    const float* src; __bf16* dst;
    if (i < 524288)        { src = x    + i*4;                    dst = xb  + i*4; }
    else if (i < 655360)   { long j = i -  524288; src = wq  + j*4; dst = wb + j*4; }
    else if (i < 786432)   { long j = i -  655360; src = wk  + j*4; dst = wb +  524288 + j*4; }
    else if (i < 1048576)  { long j = i -  786432; src = wv  + j*4; dst = wb + 1048576 + j*4; }
    else if (i < 1310720)  { long j = i - 1048576; src = wog + j*4; dst = wb + 2097152 + j*4; }
    else                   { long j = i - 1310720; src = wout+ j*4; dst = wob + j*4; }
    float4 v = *(const float4*)src;
    __bf16 o[4];
    o[0] = (__bf16)v.x; o[1] = (__bf16)v.y; o[2] = (__bf16)v.z; o[3] = (__bf16)v.w;
    *(short4*)dst = *(const short4*)o;
  } else {
    const int row = blockIdx.x - 6144;
    const int w = threadIdx.x >> 6;
    const int l = threadIdx.x & 63;
    const float* xr = x + (size_t)row * ND;
    float xv[16];
    #pragma unroll
    for (int t = 0; t < 16; ++t) xv[t] = xr[l + 64*t];
    for (int hh = 0; hh < 2; ++hh) {
      int h = w*2 + hh;
      const float* wi = Wi + (size_t)h * ND;
      const float* wf = Wf + (size_t)h * ND;
      float si = 0.f, sf = 0.f;
      #pragma unroll
      for (int t = 0; t < 16; ++t) {
        si += xv[t] * wi[l + 64*t];
        sf += xv[t] * wf[l + 64*t];
      }
      #pragma unroll
      for (int off = 32; off; off >>= 1) {
        si += __shfl_xor(si, off, 64);
        sf += __shfl_xor(sf, off, 64);
      }
      if (l == 0) {
        float ic = 15.f * tanhf((si + bi[h]) * (1.f/15.f));
        float fc = 15.f * tanhf((sf + bf_[h]) * (1.f/15.f));
        float fl = (fc >= 0.f) ? -log1pf(__expf(-fc)) : (fc - log1pf(__expf(fc)));
        icap[row*NH + h] = ic;
        flog[row*NH + h] = fl;
      }
    }
  }
}

// ---------------- shared staging: A = 128 rows (1024 slots), B = 64 rows (512 slots) ----------------
#define STAGE_AB(Abuf, Bbuf, Aptr, Bptr, Krun, ktv)                           \
  do {                                                                        \
    _Pragma("unroll")                                                         \
    for (int i_ = 0; i_ < 4; ++i_) {                                          \
      const int sb_ = i_ * 256 + wid * 64;                                    \
      const int s_ = sb_ + lane;                                              \
      const int row_ = s_ >> 3;                                               \
      const int klog_ = (s_ & 7) ^ (row_ & 7);                                \
      GLDS16(Aptr + (size_t)(m0 + row_) * Krun + (ktv) * 64 + klog_ * 8, Abuf + sb_ * 8); \
      if (i_ < 2)                                                             \
        GLDS16(Bptr + (size_t)(n0 + row_) * Krun + (ktv) * 64 + klog_ * 8, Bbuf + sb_ * 8); \
    }                                                                         \
  } while (0)

// ---------------- generic bf16 GEMM, C[M,N] = A[M,K]*B[N,K]^T, f32 out ----------------
__global__ __launch_bounds__(256) void gemm_bt(const __bf16* __restrict__ A,
                                               const __bf16* __restrict__ Bm,
                                               float* __restrict__ C,
                                               int M, int N, int K, int ntn, int nwg) {
  __shared__ __bf16 smA[2][128 * 64];
  __shared__ __bf16 smB[2][64 * 64];
  const int wg = xcd_swz(blockIdx.x, nwg);
  const int m0 = (wg / ntn) * 128;
  const int n0 = (wg % ntn) * 64;
  const int tid = threadIdx.x;
  const int wid = tid >> 6, lane = tid & 63;
  const int wm = (wid >> 1) * 64, wn = (wid & 1) * 32;
  const int fr = lane & 15;
  const int g  = lane >> 4;
  f32x4 acc[4][2] = {};
  const int NT = K >> 6;
  STAGE_AB(smA[0], smB[0], A, Bm, K, 0);
  int cur = 0;
  for (int kt = 0; kt < NT; ++kt) {
    __syncthreads();
    if (kt + 1 < NT) STAGE_AB(smA[cur ^ 1], smB[cur ^ 1], A, Bm, K, kt + 1);
    #pragma unroll
    for (int kk = 0; kk < 2; ++kk) {
      const int kg = kk * 4 + g;
      bf16x8 af[4], bfv[2];
      #pragma unroll
      for (int f = 0; f < 4; ++f) {
        const int Ra = wm + f * 16 + fr;
        af[f] = *(const bf16x8*)&smA[cur][Ra * 64 + ((kg ^ (Ra & 7)) * 8)];
      }
      #pragma unroll
      for (int n = 0; n < 2; ++n) {
        const int Rb = wn + n * 16 + fr;
        bfv[n] = *(const bf16x8*)&smB[cur][Rb * 64 + ((kg ^ (Rb & 7)) * 8)];
      }
      #pragma unroll
      for (int i = 0; i < 4; ++i)
        #pragma unroll
        for (int j = 0; j < 2; ++j)
          acc[i][j] = __builtin_amdgcn_mfma_f32_16x16x32_bf16(af[i], bfv[j], acc[i][j], 0, 0, 0);
    }
    cur ^= 1;
  }
  const int orow = m0 + wm + g * 4;
  const int ocol = n0 + wn + fr;
  #pragma unroll
  for (int i = 0; i < 4; ++i)
    #pragma unroll
    for (int j = 0; j < 2; ++j)
      #pragma unroll
      for (int r = 0; r < 4; ++r)
        C[(size_t)(orow + i*16 + r) * N + (ocol + j*16)] = acc[i][j][r];
}

// ---------------- projection GEMM with format-aware epilogue ----------------
__global__ __launch_bounds__(256) void gemm_proj(const __bf16* __restrict__ A,
    const __bf16* __restrict__ Bm,
    __bf16* __restrict__ qh, __bf16* __restrict__ ql,
    __bf16* __restrict__ kh, __bf16* __restrict__ kl,
    __bf16* __restrict__ kT, __bf16* __restrict__ vT,
    _Float16* __restrict__ ogs) {
  __shared__ __bf16 smA[2][128 * 64];
  __shared__ __bf16 smB[2][64 * 64];
  const int wg = xcd_swz(blockIdx.x, 768);
  const int m0 = (wg / 48) * 128;
  const int n0 = (wg % 48) * 64;
  const int tid = threadIdx.x;
  const int wid = tid >> 6, lane = tid & 63;
  const int wm = (wid >> 1) * 64, wn = (wid & 1) * 32;
  const int fr = lane & 15;
  const int g  = lane >> 4;
  f32x4 acc[4][2] = {};
  STAGE_AB(smA[0], smB[0], A, Bm, 1024, 0);
  int cur = 0;
  for (int kt = 0; kt < 16; ++kt) {
    __syncthreads();
    if (kt + 1 < 16) STAGE_AB(smA[cur ^ 1], smB[cur ^ 1], A, Bm, 1024, kt + 1);
    #pragma unroll
    for (int kk = 0; kk < 2; ++kk) {
      const int kg = kk * 4 + g;
      bf16x8 af[4], bfv[2];
      #pragma unroll
      for (int f = 0; f < 4; ++f) {
        const int Ra = wm + f * 16 + fr;
        af[f] = *(const bf16x8*)&smA[cur][Ra * 64 + ((kg ^ (Ra & 7)) * 8)];
      }
      #pragma unroll
      for (int n = 0; n < 2; ++n) {
        const int Rb = wn + n * 16 + fr;
        bfv[n] = *(const bf16x8*)&smB[cur][Rb * 64 + ((kg ^ (Rb & 7)) * 8)];
      }
      #pragma unroll
      for (int i = 0; i < 4; ++i)
        #pragma unroll
        for (int j = 0; j < 2; ++j)
          acc[i][j] = __builtin_amdgcn_mfma_f32_16x16x32_bf16(af[i], bfv[j], acc[i][j], 0, 0, 0);
    }
    cur ^= 1;
  }
  const int orow = m0 + wm + g * 4;
  const int ocol = n0 + wn + fr;
  const int rng = n0 >> 9;   // 0: q, 1: k, 2..3: v, 4..5: og
  if (rng == 0 || rng == 1) {
    __bf16* Hb = (rng == 0) ? qh : kh;
    __bf16* Lb = (rng == 0) ? ql : kl;
    const float sc = (rng == 0) ? 0.125f : 1.0f;
    #pragma unroll
    for (int i = 0; i < 4; ++i)
      #pragma unroll
      for (int j = 0; j < 2; ++j) {
        const int col = (ocol + j*16) & 511;      // within tensor
        const int d = col & 63;
        const int hb = col & ~63;
        __bf16 t4[4];
        #pragma unroll
        for (int r = 0; r < 4; ++r) {
          const int row = orow + i*16 + r;
          float v = acc[i][j][r] * sc;
          __bf16 hi, lo; split_bf16(v, hi, lo);
          t4[r] = hi;
          const int off = row*512 + hb + ((((d>>3) ^ (row&7))) << 3) + (d & 7);
          Hb[off] = hi;
          Lb[off] = lo;
        }
        if (rng == 1) {
          const int row0r = orow + i*16;
          const int bh = ((row0r >> 10) << 3) + (col >> 6);
          const int c = (row0r >> 6) & 15;
          const int s0 = (row0r & 63);
          const int off = ((bh*16 + c)*64 + d)*64 + (((s0>>3) ^ (d&7)) << 3) + (s0 & 7);
          *(short4*)&kT[off] = *(const short4*)t4;
        }
      }
  } else if (rng == 2 || rng == 3) {
    #pragma unroll
    for (int i = 0; i < 4; ++i)
      #pragma unroll
      for (int j = 0; j < 2; ++j) {
        const int col = (ocol + j*16) & 1023;
        const int u = col & 127;
        __bf16 t4[4];
        #pragma unroll
        for (int r = 0; r < 4; ++r) t4[r] = (__bf16)acc[i][j][r];
        const int row0r = orow + i*16;
        const int bh = ((row0r >> 10) << 3) + (col >> 7);
        const int c = (row0r >> 6) & 15;
        const int s0 = (row0r & 63);
        const int off = ((bh*16 + c)*128 + u)*64 + (((s0>>3) ^ (u&7)) << 3) + (s0 & 7);
        *(short4*)&vT[off] = *(const short4*)t4;
      }
  } else {
    #pragma unroll
    for (int i = 0; i < 4; ++i)
      #pragma unroll
      for (int j = 0; j < 2; ++j) {
        const int col = (ocol + j*16) & 1023;
        #pragma unroll
        for (int r = 0; r < 4; ++r) {
          const int row = orow + i*16 + r;
          float sg = 1.f / (1.f + __expf(-acc[i][j][r]));
          ogs[(size_t)row*1024 + col] = (_Float16)sg;
        }
      }
  }
}

// ---------------- gate scan: per (b,h), chunked cumsum/cummax ----------------
__global__ __launch_bounds__(64) void gates_kernel(const float* __restrict__ icap,
    const float* __restrict__ flog, float* __restrict__ g_g, float* __restrict__ a_g,
    float* __restrict__ m_g, float* __restrict__ m0g) {
  const int bh = blockIdx.x;
  const int b = bh >> 3, h = bh & 7;
  const int l = threadIdx.x;
  float m0 = 0.f;
  for (int c = 0; c < NCHUNK; ++c) {
    const int t = c*CHUNK + l;
    const int row = b*NS + t;
    float B = flog[row*NH + h];
    float iv = icap[row*NH + h];
    #pragma unroll
    for (int d = 1; d < 64; d <<= 1) {
      float o = __shfl_up(B, d, 64);
      if (l >= d) B += o;
    }
    float g = iv - B;
    float cm = g;
    #pragma unroll
    for (int d = 1; d < 64; d <<= 1) {
      float o = __shfl_up(cm, d, 64);
      if (l >= d) cm = fmaxf(cm, o);
    }
    float a = fmaxf(m0, cm);
    float m = B + a;
    const int idx = bh*NS + t;
    g_g[idx] = g; a_g[idx] = a; m_g[idx] = m;
    if (l == 0) m0g[bh*NCHUNK + c] = m0;
    m0 = __shfl(m, 63, 64);
  }
}

// ---------------- per-chunk U^T[u][d] via MFMA, direct-to-register frag reads ----------------
__global__ __launch_bounds__(256) void u_kernel(const __bf16* __restrict__ kT,
    const __bf16* __restrict__ vT, const float* __restrict__ g_g,
    const float* __restrict__ a_g, float* __restrict__ Ut, float* __restrict__ Ung) {
  __shared__ float w_l[64];
  const int task = blockIdx.x;
  const int bh = task >> 4, c = task & 15;
  const int t = threadIdx.x;
  const int wid = t >> 6, lane = t & 63;
  const int fr = lane & 15, g = lane >> 4;
  if (t < 64) {
    const float aL = a_g[bh*NS + c*CHUNK + 63];
    w_l[t] = __expf(g_g[bh*NS + c*CHUNK + t] - aL);
  }
  __syncthreads();
  const __bf16* ktb = kT + (size_t)task * 4096;
  const __bf16* vtb = vT + (size_t)task * 8192;
  f32x4 acc[8] = {};
  #pragma unroll
  for (int kk = 0; kk < 2; ++kk) {
    const int kg = kk*4 + g;
    const int Ra = wid*16 + fr;
    bf16x8 afr = *(const bf16x8*)&ktb[Ra*64 + ((kg ^ (Ra & 7)) * 8)];
    bf16x8 afw;
    #pragma unroll
    for (int j = 0; j < 8; ++j) afw[j] = (__bf16)((float)afr[j] * w_l[kg*8 + j]);
    #pragma unroll
    for (int nt = 0; nt < 8; ++nt) {
      const int Rb = nt*16 + fr;
      bf16x8 bv = *(const bf16x8*)&vtb[Rb*64 + ((kg ^ (Rb & 7)) * 8)];
      acc[nt] = __builtin_amdgcn_mfma_f32_16x16x32_bf16(afw, bv, acc[nt], 0, 0, 0);
    }
  }
  float* ub = Ut + (size_t)task * 8192;
  #pragma unroll
  for (int nt = 0; nt < 8; ++nt) {
    const int u = nt*16 + fr;
    *(f32x4*)&ub[u*64 + wid*16 + g*4] = acc[nt];
  }
  if (t < 64) {
    float s = 0.f;
    #pragma unroll
    for (int blk = 0; blk < 8; ++blk) {
      bf16x8 kv = *(const bf16x8*)&ktb[t*64 + ((blk ^ (t & 7)) * 8)];
      #pragma unroll
      for (int j = 0; j < 8; ++j) s += (float)kv[j] * w_l[blk*8 + j];
    }
    Ung[task*64 + t] = s;
  }
}

// ---------------- inter-chunk state prefix scan (spread across all CUs) ----------------
__global__ __launch_bounds__(64) void statescan_kernel(const float* __restrict__ Ut,
    const float* __restrict__ Ung, const float* __restrict__ m0g,
    const float* __restrict__ a_g, __bf16* __restrict__ C0T, float* __restrict__ n0g) {
  const int bh = blockIdx.x >> 4, part = blockIdx.x & 15;
  const int e8 = part*64 + threadIdx.x;      // 0..1023: group of 8 d for one u
  const int u = e8 >> 3, d8 = e8 & 7;
  const int dsto = u*64 + ((d8 ^ (u & 7)) << 3);
  const int srco = u*64 + d8*8;
  float scale[NCHUNK];
  #pragma unroll
  for (int c = 0; c < NCHUNK; ++c)
    scale[c] = __expf(m0g[bh*NCHUNK + c] - a_g[bh*NS + c*CHUNK + 63]);
  float val[8] = {};
  for (int c = 0; c < NCHUNK; ++c) {
    const size_t base = ((size_t)(bh*NCHUNK + c)) * 8192;
    __bf16 o[8];
    #pragma unroll
    for (int j = 0; j < 8; ++j) o[j] = (__bf16)val[j];
    *(float4*)&C0T[base + dsto] = *(const float4*)o;
    f32x4 u0 = *(const f32x4*)&Ut[base + srco];
    f32x4 u1 = *(const f32x4*)&Ut[base + srco + 4];
    #pragma unroll
    for (int j = 0; j < 4; ++j) {
      val[j]   = scale[c]*val[j]   + u0[j];
      val[j+4] = scale[c]*val[j+4] + u1[j];
    }
  }
  if (part == 0) {
    float nv = 0.f;
    for (int c = 0; c < NCHUNK; ++c) {
      int idx = (bh*NCHUNK + c)*64 + threadIdx.x;
      n0g[idx] = nv;
      nv = scale[c]*nv + Ung[idx];
    }
  }
}

// ---------------- intra-chunk attention + inter + denom + LN + gate ----------------
// Direct-to-register global frag reads (buffers are pre-swizzled); LDS only for
// Ps (cross-wave P exchange) + cross-wave scalars. 3 barriers.
__global__ __launch_bounds__(256) void intra_kernel(
    const __bf16* __restrict__ qh, const __bf16* __restrict__ ql,
    const __bf16* __restrict__ kh, const __bf16* __restrict__ kl,
    const __bf16* __restrict__ vT, const __bf16* __restrict__ C0T,
    const _Float16* __restrict__ ogs,
    const float* __restrict__ g_g, const float* __restrict__ a_g,
    const float* __restrict__ m_g, const float* __restrict__ m0g,
    const float* __restrict__ n0g,
    const float* __restrict__ gamma, __bf16* __restrict__ hout) {
  __shared__ __bf16 Ps[32*72];
  __shared__ float g_l[64], n0_l[64], a_l[32], m_l[32], cI_l[32];
  __shared__ float qnA[2][32], qnI_l[32], lnS[2][32], lnQ[2][32];

  const int blk = blockIdx.x;
  const int task = blk >> 1, jhalf = blk & 1;
  const int bh = task >> 4, c = task & 15;
  const int b = bh >> 3, h = bh & 7;
  const int t = threadIdx.x;
  const int wid = t >> 6, lane = t & 63;
  const int fr = lane & 15, lg = lane >> 4;
  const int jt_local = wid >> 1, half = wid & 1;
  const int jtg = jhalf*2 + jt_local;
  const int row0 = b*NS + c*CHUNK;
  const int jrow0 = row0 + jhalf*32;
  const __bf16* vtb = vT + (size_t)task * 8192;
  const __bf16* c0b = C0T + (size_t)task * 8192;

  const float m0v = m0g[bh*NCHUNK + c];
  if (t < 64) {
    g_l[t]  = g_g[bh*NS + c*CHUNK + t];
    n0_l[t] = n0g[task*64 + t];
  } else if (t < 96) {
    int jl = t - 64;
    float av = a_g[bh*NS + c*CHUNK + jhalf*32 + jl];
    a_l[jl] = av;
    m_l[jl] = m_g[bh*NS + c*CHUNK + jhalf*32 + jl];
    cI_l[jl] = __expf(m0v - av);
  }
  __syncthreads();

  // ---- q frags (register-resident, reused across phases)
  const int Ra = jt_local*16 + fr;
  const size_t qrow = (size_t)(jrow0 + Ra)*512 + h*64;
  bf16x8 qhv[2], qlv[2];
  #pragma unroll
  for (int kk = 0; kk < 2; ++kk) {
    const int kg = kk*4 + lg;
    const int off = (kg ^ (Ra & 7)) * 8;
    qhv[kk] = *(const bf16x8*)&qh[qrow + off];
    qlv[kk] = *(const bf16x8*)&ql[qrow + off];
  }

  // ---- Phase A: QK^T (hi/lo), mask+exp, row sums, P->bf16
  float rsum[4] = {0.f, 0.f, 0.f, 0.f};
  for (int st = half; st < 4; st += 2) {
    if (st <= jtg) {
      f32x4 sacc = {};
      const int Rb = st*16 + fr;
      const size_t krow = (size_t)(row0 + Rb)*512 + h*64;
      #pragma unroll
      for (int kk = 0; kk < 2; ++kk) {
        const int kg = kk*4 + lg;
        const int offb = (kg ^ (Rb & 7)) * 8;
        bf16x8 khv = *(const bf16x8*)&kh[krow + offb];
        bf16x8 klv = *(const bf16x8*)&kl[krow + offb];
        sacc = __builtin_amdgcn_mfma_f32_16x16x32_bf16(qhv[kk], khv, sacc, 0, 0, 0);
        sacc = __builtin_amdgcn_mfma_f32_16x16x32_bf16(qhv[kk], klv, sacc, 0, 0, 0);
        sacc = __builtin_amdgcn_mfma_f32_16x16x32_bf16(qlv[kk], khv, sacc, 0, 0, 0);
      }
      const int s_c = st*16 + fr;
      const float gs = g_l[s_c];
      #pragma unroll
      for (int r = 0; r < 4; ++r) {
        const int jl = jt_local*16 + lg*4 + r;
        const int j_c = jhalf*32 + jl;
        float w = (s_c <= j_c) ? __expf(gs - a_l[jl]) : 0.f;
        float p = sacc[r] * w;
        rsum[r] += p;
        Ps[jl*72 + s_c] = (__bf16)p;
      }
    } else {
      #pragma unroll
      for (int r = 0; r < 4; ++r)
        Ps[(jt_local*16 + lg*4 + r)*72 + st*16 + fr] = (__bf16)0.f;
    }
  }
  #pragma unroll
  for (int r = 0; r < 4; ++r) {
    #pragma unroll
    for (int off = 1; off < 16; off <<= 1) rsum[r] += __shfl_xor(rsum[r], off, 64);
  }
  if (fr == 0) {
    #pragma unroll
    for (int r = 0; r < 4; ++r) qnA[half][jt_local*16 + lg*4 + r] = rsum[r];
  }

  // ---- inter term: acc[j][u] = q_hi . C0T, then * cI[j]
  f32x4 acc[4] = {};
  #pragma unroll
  for (int kk = 0; kk < 2; ++kk) {
    const int kg = kk*4 + lg;
    #pragma unroll
    for (int nt = 0; nt < 4; ++nt) {
      const int Rb = (half*4 + nt)*16 + fr;
      bf16x8 bc = *(const bf16x8*)&c0b[Rb*64 + ((kg ^ (Rb&7))*8)];
      acc[nt] = __builtin_amdgcn_mfma_f32_16x16x32_bf16(qhv[kk], bc, acc[nt], 0, 0, 0);
    }
  }
  {
    float ci4[4];
    #pragma unroll
    for (int r = 0; r < 4; ++r) ci4[r] = cI_l[jt_local*16 + lg*4 + r];
    #pragma unroll
    for (int nt = 0; nt < 4; ++nt)
      #pragma unroll
      for (int r = 0; r < 4; ++r) acc[nt][r] *= ci4[r];
  }
  // ---- qn_inter (half==1 waves): cI[j] * sum_d q[j][d]*n0[d]
  if (half == 1) {
    const int jl = jt_local*16 + fr;
    const size_t qr2 = (size_t)(jrow0 + jl)*512 + h*64;
    float s = 0.f;
    #pragma unroll
    for (int i = 0; i < 16; ++i) {
      const int d = lg*16 + i;
      const int off = (((d>>3) ^ (jl&7)) << 3) + (d & 7);
      float qv = (float)qh[qr2 + off] + (float)ql[qr2 + off];
      s += qv * n0_l[d];
    }
    s += __shfl_xor(s, 16, 64);
    s += __shfl_xor(s, 32, 64);
    if (lane < 16) qnI_l[jl] = cI_l[jl] * s;
  }
  __syncthreads();   // Ps/qnA/qnI visibility

  // ---- PV: acc += Ps . vT
  #pragma unroll
  for (int kk = 0; kk < 2; ++kk) {
    const int kg = kk*4 + lg;
    bf16x8 ap = *(const bf16x8*)&Ps[(jt_local*16 + fr)*72 + kg*8];
    #pragma unroll
    for (int nt = 0; nt < 4; ++nt) {
      const int Rb = (half*4 + nt)*16 + fr;
      bf16x8 bv = *(const bf16x8*)&vtb[Rb*64 + ((kg ^ (Rb&7))*8)];
      acc[nt] = __builtin_amdgcn_mfma_f32_16x16x32_bf16(ap, bv, acc[nt], 0, 0, 0);
    }
  }

  // ---- epilogue part 1: denom + LN partials
  #pragma unroll
  for (int r = 0; r < 4; ++r) {
    const int jl = jt_local*16 + lg*4 + r;
    float qn = qnA[0][jl] + qnA[1][jl] + qnI_l[jl];
    float denom = fmaxf(fabsf(qn), __expf(-m_l[jl])) + 1e-6f;
    float rd = 1.f / denom;
    float s = 0.f, q2 = 0.f;
    #pragma unroll
    for (int nt = 0; nt < 4; ++nt) {
      float hv = acc[nt][r] * rd;
      acc[nt][r] = hv;
      s += hv; q2 += hv*hv;
    }
    #pragma unroll
    for (int off = 1; off < 16; off <<= 1) {
      s  += __shfl_xor(s,  off, 64);
      q2 += __shfl_xor(q2, off, 64);
    }
    if (fr == 0) { lnS[half][jl] = s; lnQ[half][jl] = q2; }
  }
  __syncthreads();

  // ---- epilogue part 2: LN + output gate + bf16 store
  #pragma unroll
  for (int r = 0; r < 4; ++r) {
    const int jl = jt_local*16 + lg*4 + r;
    float sm = lnS[0][jl] + lnS[1][jl];
    float sq = lnQ[0][jl] + lnQ[1][jl];
    float mu = sm * (1.f/128.f);
    float var = sq * (1.f/128.f) - mu*mu;
    float rstd = rsqrtf(var + 1e-6f);
    const int rowg = jrow0 + jl;
    #pragma unroll
    for (int nt = 0; nt < 4; ++nt) {
      const int u = (half*4 + nt)*16 + fr;
      float sg = (float)ogs[(size_t)rowg*1024 + h*DHV + u];
      float hn = (acc[nt][r] - mu) * rstd * gamma[h*DHV + u] * sg;
      hout[(size_t)rowg*NV + h*DHV + u] = (__bf16)hn;
    }
  }
}

extern "C" void kernel_launch(void* const* d_in, const int* in_sizes, int n_in,
                              void* d_out, int out_size, void* d_ws, size_t ws_size,
                              hipStream_t stream) {
  const float* x    = (const float*)d_in[0];
  const float* Wq   = (const float*)d_in[1];
  const float* Wk   = (const float*)d_in[2];
  const float* Wv   = (const float*)d_in[3];
  const float* Wog  = (const float*)d_in[4];
  const float* Wi   = (const float*)d_in[5];
  const float* bi   = (const float*)d_in[6];
  const float* Wf   = (const float*)d_in[7];
  const float* bf_  = (const float*)d_in[8];
  const float* gamma= (const float*)d_in[9];
  const float* Wout = (const float*)d_in[10];
  float* y = (float*)d_out;

  char* ws = (char*)d_ws;
  const size_t MB = 1u << 20;
  __bf16*   xb   = (__bf16*)  (ws + 0);        // 4 MB
  __bf16*   Wb   = (__bf16*)  (ws + 4*MB);     // 6 MB
  __bf16*   Wob  = (__bf16*)  (ws + 10*MB);    // 2 MB
  __bf16*   qh   = (__bf16*)  (ws + 12*MB);    // 2 MB  [2048][512] swz
  __bf16*   ql   = (__bf16*)  (ws + 14*MB);    // 2 MB
  __bf16*   kh   = (__bf16*)  (ws + 16*MB);    // 2 MB
  __bf16*   kl   = (__bf16*)  (ws + 18*MB);    // 2 MB
  __bf16*   kT   = (__bf16*)  (ws + 20*MB);    // 2 MB  [256][64][64] swz
  __bf16*   vT   = (__bf16*)  (ws + 22*MB);    // 4 MB  [256][128][64] swz
  _Float16* ogs  = (_Float16*)(ws + 26*MB);    // 4 MB  [2048][1024] sigmoid
  float*    Ut   = (float*)   (ws + 30*MB);    // 8 MB  [256][128][64]
  __bf16*   C0T  = (__bf16*)  (ws + 38*MB);    // 4 MB  [256][128][64] swz
  float*    icap = (float*)   (ws + 42*MB);
  float*    flog = (float*)   (ws + 42*MB + 64*1024);
  float*    g_g  = (float*)   (ws + 42*MB + 128*1024);
  float*    a_g  = (float*)   (ws + 42*MB + 192*1024);
  float*    m_g  = (float*)   (ws + 42*MB + 256*1024);
  float*    m0g  = (float*)   (ws + 42*MB + 320*1024);
  float*    Ung  = (float*)   (ws + 42*MB + 384*1024);
  float*    n0g  = (float*)   (ws + 42*MB + 448*1024);
  __bf16*   houtb= (__bf16*)  (ws + 44*MB);    // 4 MB

  prep_kernel<<<8192, 256, 0, stream>>>(x, Wq, Wk, Wv, Wog, Wout, Wi, bi, Wf, bf_,
                                        xb, Wb, Wob, icap, flog);

  gemm_proj<<<768, 256, 0, stream>>>(xb, Wb, qh, ql, kh, kl, kT, vT, ogs);

  gates_kernel<<<16, 64, 0, stream>>>(icap, flog, g_g, a_g, m_g, m0g);
  u_kernel<<<256, 256, 0, stream>>>(kT, vT, g_g, a_g, Ut, Ung);
  statescan_kernel<<<256, 64, 0, stream>>>(Ut, Ung, m0g, a_g, C0T, n0g);
  intra_kernel<<<512, 256, 0, stream>>>(qh, ql, kh, kl, vT, C0T, ogs,
                                        g_g, a_g, m_g, m0g, n0g, gamma, houtb);

  gemm_bt<<<256, 256, 0, stream>>>(houtb, Wob, y, 2048, 1024, 1024, 16, 256);
}

// Round 10
// 161.921 us; speedup vs baseline: 1.1319x; 1.0093x over previous
//
#include <hip/hip_runtime.h>
#include <hip/hip_bf16.h>
#include <math.h>

typedef __bf16 bf16x8 __attribute__((ext_vector_type(8)));
typedef float f32x4 __attribute__((ext_vector_type(4)));

#define NB 2
#define NS 1024
#define ND 1024
#define NH 8
#define NQK 512
#define NV 1024
#define DQK 64
#define DHV 128
#define CHUNK 64
#define NCHUNK 16

#define GLDS16(g, l) __builtin_amdgcn_global_load_lds((const __attribute__((address_space(1))) void*)(g), (__attribute__((address_space(3))) void*)(l), 16, 0, 0)

static __device__ __forceinline__ void split_bf16(float v, __bf16& hi, __bf16& lo) {
  hi = (__bf16)v;
  lo = (__bf16)(v - (float)hi);
}

// bijective XCD swizzle (m204)
static __device__ __forceinline__ int xcd_swz(int orig, int nwg) {
  int q = nwg >> 3, r = nwg & 7;
  int xcd = orig & 7, idx = orig >> 3;
  int base = (xcd < r) ? xcd * (q + 1) : r * (q + 1) + (xcd - r) * q;
  return base + idx;
}

// ---------------- fused prep: f32->bf16 cvt (blocks 0..6143) + i/f gates (6144..8191) ----------------
__global__ __launch_bounds__(256) void prep_kernel(const float* __restrict__ x,
    const float* __restrict__ wq, const float* __restrict__ wk,
    const float* __restrict__ wv, const float* __restrict__ wog,
    const float* __restrict__ wout,
    const float* __restrict__ Wi, const float* __restrict__ bi,
    const float* __restrict__ Wf, const float* __restrict__ bf_,
    __bf16* __restrict__ xb, __bf16* __restrict__ wb, __bf16* __restrict__ wob,
    float* __restrict__ icap, float* __restrict__ flog) {
  if (blockIdx.x < 6144) {
    long i = (long)blockIdx.x * 256 + threadIdx.x;   // float4 index
    const float* src; __bf16* dst;
    if (i < 524288)        { src = x    + i*4;                    dst = xb  + i*4; }
    else if (i < 655360)   { long j = i -  524288; src = wq  + j*4; dst = wb + j*4; }
    else if (i < 786432)   { long j = i -  655360; src = wk  + j*4; dst = wb +  524288 + j*4; }
    else if (i < 1048576)  { long j = i -  786432; src = wv  + j*4; dst = wb + 1048576 + j*4; }
    else if (i < 1310720)  { long j = i - 1048576; src = wog + j*4; dst = wb + 2097152 + j*4; }
    else                   { long j = i - 1310720; src = wout+ j*4; dst = wob + j*4; }
    float4 v = *(const float4*)src;
    __bf16 o[4];
    o[0] = (__bf16)v.x; o[1] = (__bf16)v.y; o[2] = (__bf16)v.z; o[3] = (__bf16)v.w;
    *(short4*)dst = *(const short4*)o;
  } else {
    const int row = blockIdx.x - 6144;
    const int w = threadIdx.x >> 6;
    const int l = threadIdx.x & 63;
    const float* xr = x + (size_t)row * ND;
    float xv[16];
    #pragma unroll
    for (int t = 0; t < 16; ++t) xv[t] = xr[l + 64*t];
    for (int hh = 0; hh < 2; ++hh) {
      int h = w*2 + hh;
      const float* wi = Wi + (size_t)h * ND;
      const float* wf = Wf + (size_t)h * ND;
      float si = 0.f, sf = 0.f;
      #pragma unroll
      for (int t = 0; t < 16; ++t) {
        si += xv[t] * wi[l + 64*t];
        sf += xv[t] * wf[l + 64*t];
      }
      #pragma unroll
      for (int off = 32; off; off >>= 1) {
        si += __shfl_xor(si, off, 64);
        sf += __shfl_xor(sf, off, 64);
      }
      if (l == 0) {
        float ic = 15.f * tanhf((si + bi[h]) * (1.f/15.f));
        float fc = 15.f * tanhf((sf + bf_[h]) * (1.f/15.f));
        float fl = (fc >= 0.f) ? -log1pf(__expf(-fc)) : (fc - log1pf(__expf(fc)));
        icap[row*NH + h] = ic;
        flog[row*NH + h] = fl;
      }
    }
  }
}

// ---------------- staging: A = 128 rows (1024 slots), B = 64 rows (512 slots) ----------------
#define STAGE_AB(Abuf, Bbuf, Aptr, Bptr, Krun, ktv)                           \
  do {                                                                        \
    _Pragma("unroll")                                                         \
    for (int i_ = 0; i_ < 4; ++i_) {                                          \
      const int sb_ = i_ * 256 + wid * 64;                                    \
      const int s_ = sb_ + lane;                                              \
      const int row_ = s_ >> 3;                                               \
      const int klog_ = (s_ & 7) ^ (row_ & 7);                                \
      GLDS16(Aptr + (size_t)(m0 + row_) * Krun + (ktv) * 64 + klog_ * 8, Abuf + sb_ * 8); \
      if (i_ < 2)                                                             \
        GLDS16(Bptr + (size_t)(n0 + row_) * Krun + (ktv) * 64 + klog_ * 8, Bbuf + sb_ * 8); \
    }                                                                         \
  } while (0)

// ---------------- staging for 64x64 tiles: A,B = 64 rows (512 slots each) ----------------
#define STAGE64(Abuf, Bbuf, Aptr, Bptr, Krun, ktv)                            \
  do {                                                                        \
    _Pragma("unroll")                                                         \
    for (int i_ = 0; i_ < 2; ++i_) {                                          \
      const int sb_ = i_ * 256 + wid * 64;                                    \
      const int s_ = sb_ + lane;                                              \
      const int row_ = s_ >> 3;                                               \
      const int klog_ = (s_ & 7) ^ (row_ & 7);                                \
      GLDS16(Aptr + (size_t)(m0 + row_) * Krun + (ktv) * 64 + klog_ * 8, Abuf + sb_ * 8); \
      GLDS16(Bptr + (size_t)(n0 + row_) * Krun + (ktv) * 64 + klog_ * 8, Bbuf + sb_ * 8); \
    }                                                                         \
  } while (0)

// ---------------- generic bf16 GEMM, C[M,N] = A[M,K]*B[N,K]^T, f32 out ----------------
// 64x64 tile, 4 waves (wave tile 32x32), BK=64 dbuf, 2 blocks/CU.
__global__ __launch_bounds__(256) void gemm_bt(const __bf16* __restrict__ A,
                                               const __bf16* __restrict__ Bm,
                                               float* __restrict__ C,
                                               int M, int N, int K, int ntn, int nwg) {
  __shared__ __bf16 smA[2][64 * 64];
  __shared__ __bf16 smB[2][64 * 64];
  const int wg = xcd_swz(blockIdx.x, nwg);
  const int m0 = (wg / ntn) * 64;
  const int n0 = (wg % ntn) * 64;
  const int tid = threadIdx.x;
  const int wid = tid >> 6, lane = tid & 63;
  const int wm = (wid >> 1) * 32, wn = (wid & 1) * 32;
  const int fr = lane & 15;
  const int g  = lane >> 4;
  f32x4 acc[2][2] = {};
  const int NT = K >> 6;
  STAGE64(smA[0], smB[0], A, Bm, K, 0);
  int cur = 0;
  for (int kt = 0; kt < NT; ++kt) {
    __syncthreads();
    if (kt + 1 < NT) STAGE64(smA[cur ^ 1], smB[cur ^ 1], A, Bm, K, kt + 1);
    #pragma unroll
    for (int kk = 0; kk < 2; ++kk) {
      const int kg = kk * 4 + g;
      bf16x8 af[2], bfv[2];
      #pragma unroll
      for (int f = 0; f < 2; ++f) {
        const int Ra = wm + f * 16 + fr;
        af[f] = *(const bf16x8*)&smA[cur][Ra * 64 + ((kg ^ (Ra & 7)) * 8)];
      }
      #pragma unroll
      for (int n = 0; n < 2; ++n) {
        const int Rb = wn + n * 16 + fr;
        bfv[n] = *(const bf16x8*)&smB[cur][Rb * 64 + ((kg ^ (Rb & 7)) * 8)];
      }
      #pragma unroll
      for (int i = 0; i < 2; ++i)
        #pragma unroll
        for (int j = 0; j < 2; ++j)
          acc[i][j] = __builtin_amdgcn_mfma_f32_16x16x32_bf16(af[i], bfv[j], acc[i][j], 0, 0, 0);
    }
    cur ^= 1;
  }
  const int orow = m0 + wm + g * 4;
  const int ocol = n0 + wn + fr;
  #pragma unroll
  for (int i = 0; i < 2; ++i)
    #pragma unroll
    for (int j = 0; j < 2; ++j)
      #pragma unroll
      for (int r = 0; r < 4; ++r)
        C[(size_t)(orow + i*16 + r) * N + (ocol + j*16)] = acc[i][j][r];
}

// ---------------- projection GEMM with format-aware epilogue ----------------
__global__ __launch_bounds__(256) void gemm_proj(const __bf16* __restrict__ A,
    const __bf16* __restrict__ Bm,
    __bf16* __restrict__ qh, __bf16* __restrict__ ql,
    __bf16* __restrict__ kh, __bf16* __restrict__ kl,
    __bf16* __restrict__ kT, __bf16* __restrict__ vT,
    _Float16* __restrict__ ogs) {
  __shared__ __bf16 smA[2][128 * 64];
  __shared__ __bf16 smB[2][64 * 64];
  const int wg = xcd_swz(blockIdx.x, 768);
  const int m0 = (wg / 48) * 128;
  const int n0 = (wg % 48) * 64;
  const int tid = threadIdx.x;
  const int wid = tid >> 6, lane = tid & 63;
  const int wm = (wid >> 1) * 64, wn = (wid & 1) * 32;
  const int fr = lane & 15;
  const int g  = lane >> 4;
  f32x4 acc[4][2] = {};
  STAGE_AB(smA[0], smB[0], A, Bm, 1024, 0);
  int cur = 0;
  for (int kt = 0; kt < 16; ++kt) {
    __syncthreads();
    if (kt + 1 < 16) STAGE_AB(smA[cur ^ 1], smB[cur ^ 1], A, Bm, 1024, kt + 1);
    #pragma unroll
    for (int kk = 0; kk < 2; ++kk) {
      const int kg = kk * 4 + g;
      bf16x8 af[4], bfv[2];
      #pragma unroll
      for (int f = 0; f < 4; ++f) {
        const int Ra = wm + f * 16 + fr;
        af[f] = *(const bf16x8*)&smA[cur][Ra * 64 + ((kg ^ (Ra & 7)) * 8)];
      }
      #pragma unroll
      for (int n = 0; n < 2; ++n) {
        const int Rb = wn + n * 16 + fr;
        bfv[n] = *(const bf16x8*)&smB[cur][Rb * 64 + ((kg ^ (Rb & 7)) * 8)];
      }
      #pragma unroll
      for (int i = 0; i < 4; ++i)
        #pragma unroll
        for (int j = 0; j < 2; ++j)
          acc[i][j] = __builtin_amdgcn_mfma_f32_16x16x32_bf16(af[i], bfv[j], acc[i][j], 0, 0, 0);
    }
    cur ^= 1;
  }
  const int orow = m0 + wm + g * 4;
  const int ocol = n0 + wn + fr;
  const int rng = n0 >> 9;   // 0: q, 1: k, 2..3: v, 4..5: og
  if (rng == 0 || rng == 1) {
    __bf16* Hb = (rng == 0) ? qh : kh;
    __bf16* Lb = (rng == 0) ? ql : kl;
    const float sc = (rng == 0) ? 0.125f : 1.0f;
    #pragma unroll
    for (int i = 0; i < 4; ++i)
      #pragma unroll
      for (int j = 0; j < 2; ++j) {
        const int col = (ocol + j*16) & 511;      // within tensor
        const int d = col & 63;
        const int hb = col & ~63;
        __bf16 t4[4];
        #pragma unroll
        for (int r = 0; r < 4; ++r) {
          const int row = orow + i*16 + r;
          float v = acc[i][j][r] * sc;
          __bf16 hi, lo; split_bf16(v, hi, lo);
          t4[r] = hi;
          const int off = row*512 + hb + ((((d>>3) ^ (row&7))) << 3) + (d & 7);
          Hb[off] = hi;
          Lb[off] = lo;
        }
        if (rng == 1) {
          const int row0r = orow + i*16;
          const int bh = ((row0r >> 10) << 3) + (col >> 6);
          const int c = (row0r >> 6) & 15;
          const int s0 = (row0r & 63);
          const int off = ((bh*16 + c)*64 + d)*64 + (((s0>>3) ^ (d&7)) << 3) + (s0 & 7);
          *(short4*)&kT[off] = *(const short4*)t4;
        }
      }
  } else if (rng == 2 || rng == 3) {
    #pragma unroll
    for (int i = 0; i < 4; ++i)
      #pragma unroll
      for (int j = 0; j < 2; ++j) {
        const int col = (ocol + j*16) & 1023;
        const int u = col & 127;
        __bf16 t4[4];
        #pragma unroll
        for (int r = 0; r < 4; ++r) t4[r] = (__bf16)acc[i][j][r];
        const int row0r = orow + i*16;
        const int bh = ((row0r >> 10) << 3) + (col >> 7);
        const int c = (row0r >> 6) & 15;
        const int s0 = (row0r & 63);
        const int off = ((bh*16 + c)*128 + u)*64 + (((s0>>3) ^ (u&7)) << 3) + (s0 & 7);
        *(short4*)&vT[off] = *(const short4*)t4;
      }
  } else {
    #pragma unroll
    for (int i = 0; i < 4; ++i)
      #pragma unroll
      for (int j = 0; j < 2; ++j) {
        const int col = (ocol + j*16) & 1023;
        #pragma unroll
        for (int r = 0; r < 4; ++r) {
          const int row = orow + i*16 + r;
          float sg = 1.f / (1.f + __expf(-acc[i][j][r]));
          ogs[(size_t)row*1024 + col] = (_Float16)sg;
        }
      }
  }
}

// ---------------- gate scan: per (b,h), chunked cumsum/cummax ----------------
__global__ __launch_bounds__(64) void gates_kernel(const float* __restrict__ icap,
    const float* __restrict__ flog, float* __restrict__ g_g, float* __restrict__ a_g,
    float* __restrict__ m_g, float* __restrict__ m0g) {
  const int bh = blockIdx.x;
  const int b = bh >> 3, h = bh & 7;
  const int l = threadIdx.x;
  float m0 = 0.f;
  for (int c = 0; c < NCHUNK; ++c) {
    const int t = c*CHUNK + l;
    const int row = b*NS + t;
    float B = flog[row*NH + h];
    float iv = icap[row*NH + h];
    #pragma unroll
    for (int d = 1; d < 64; d <<= 1) {
      float o = __shfl_up(B, d, 64);
      if (l >= d) B += o;
    }
    float g = iv - B;
    float cm = g;
    #pragma unroll
    for (int d = 1; d < 64; d <<= 1) {
      float o = __shfl_up(cm, d, 64);
      if (l >= d) cm = fmaxf(cm, o);
    }
    float a = fmaxf(m0, cm);
    float m = B + a;
    const int idx = bh*NS + t;
    g_g[idx] = g; a_g[idx] = a; m_g[idx] = m;
    if (l == 0) m0g[bh*NCHUNK + c] = m0;
    m0 = __shfl(m, 63, 64);
  }
}

// ---------------- per-chunk U^T[u][d] via MFMA, direct-to-register frag reads ----------------
__global__ __launch_bounds__(256) void u_kernel(const __bf16* __restrict__ kT,
    const __bf16* __restrict__ vT, const float* __restrict__ g_g,
    const float* __restrict__ a_g, float* __restrict__ Ut, float* __restrict__ Ung) {
  __shared__ float w_l[64];
  const int task = blockIdx.x;
  const int bh = task >> 4, c = task & 15;
  const int t = threadIdx.x;
  const int wid = t >> 6, lane = t & 63;
  const int fr = lane & 15, g = lane >> 4;
  if (t < 64) {
    const float aL = a_g[bh*NS + c*CHUNK + 63];
    w_l[t] = __expf(g_g[bh*NS + c*CHUNK + t] - aL);
  }
  __syncthreads();
  const __bf16* ktb = kT + (size_t)task * 4096;
  const __bf16* vtb = vT + (size_t)task * 8192;
  f32x4 acc[8] = {};
  #pragma unroll
  for (int kk = 0; kk < 2; ++kk) {
    const int kg = kk*4 + g;
    const int Ra = wid*16 + fr;
    bf16x8 afr = *(const bf16x8*)&ktb[Ra*64 + ((kg ^ (Ra & 7)) * 8)];
    bf16x8 afw;
    #pragma unroll
    for (int j = 0; j < 8; ++j) afw[j] = (__bf16)((float)afr[j] * w_l[kg*8 + j]);
    #pragma unroll
    for (int nt = 0; nt < 8; ++nt) {
      const int Rb = nt*16 + fr;
      bf16x8 bv = *(const bf16x8*)&vtb[Rb*64 + ((kg ^ (Rb & 7)) * 8)];
      acc[nt] = __builtin_amdgcn_mfma_f32_16x16x32_bf16(afw, bv, acc[nt], 0, 0, 0);
    }
  }
  float* ub = Ut + (size_t)task * 8192;
  #pragma unroll
  for (int nt = 0; nt < 8; ++nt) {
    const int u = nt*16 + fr;
    *(f32x4*)&ub[u*64 + wid*16 + g*4] = acc[nt];
  }
  if (t < 64) {
    float s = 0.f;
    #pragma unroll
    for (int blk = 0; blk < 8; ++blk) {
      bf16x8 kv = *(const bf16x8*)&ktb[t*64 + ((blk ^ (t & 7)) * 8)];
      #pragma unroll
      for (int j = 0; j < 8; ++j) s += (float)kv[j] * w_l[blk*8 + j];
    }
    Ung[task*64 + t] = s;
  }
}

// ---------------- inter-chunk state prefix scan (spread across all CUs) ----------------
__global__ __launch_bounds__(64) void statescan_kernel(const float* __restrict__ Ut,
    const float* __restrict__ Ung, const float* __restrict__ m0g,
    const float* __restrict__ a_g, __bf16* __restrict__ C0T, float* __restrict__ n0g) {
  const int bh = blockIdx.x >> 4, part = blockIdx.x & 15;
  const int e8 = part*64 + threadIdx.x;      // 0..1023: group of 8 d for one u
  const int u = e8 >> 3, d8 = e8 & 7;
  const int dsto = u*64 + ((d8 ^ (u & 7)) << 3);
  const int srco = u*64 + d8*8;
  float scale[NCHUNK];
  #pragma unroll
  for (int c = 0; c < NCHUNK; ++c)
    scale[c] = __expf(m0g[bh*NCHUNK + c] - a_g[bh*NS + c*CHUNK + 63]);
  float val[8] = {};
  for (int c = 0; c < NCHUNK; ++c) {
    const size_t base = ((size_t)(bh*NCHUNK + c)) * 8192;
    __bf16 o[8];
    #pragma unroll
    for (int j = 0; j < 8; ++j) o[j] = (__bf16)val[j];
    *(float4*)&C0T[base + dsto] = *(const float4*)o;
    f32x4 u0 = *(const f32x4*)&Ut[base + srco];
    f32x4 u1 = *(const f32x4*)&Ut[base + srco + 4];
    #pragma unroll
    for (int j = 0; j < 4; ++j) {
      val[j]   = scale[c]*val[j]   + u0[j];
      val[j+4] = scale[c]*val[j+4] + u1[j];
    }
  }
  if (part == 0) {
    float nv = 0.f;
    for (int c = 0; c < NCHUNK; ++c) {
      int idx = (bh*NCHUNK + c)*64 + threadIdx.x;
      n0g[idx] = nv;
      nv = scale[c]*nv + Ung[idx];
    }
  }
}

// ---------------- intra-chunk attention + inter + denom + LN + gate ----------------
// One block per task (1024 thr, 16 waves: jt 0..3 x sl 0..3). Wave (jt,sl):
// phase A computes S-tile (jt,st=sl); inter/PV cover u-tiles sl*2..sl*2+1.
// 4096 waves total -> 4 waves/SIMD (2x round-9 TLP). 3 barriers.
__global__ __launch_bounds__(1024) void intra_kernel(
    const __bf16* __restrict__ qh, const __bf16* __restrict__ ql,
    const __bf16* __restrict__ kh, const __bf16* __restrict__ kl,
    const __bf16* __restrict__ vT, const __bf16* __restrict__ C0T,
    const _Float16* __restrict__ ogs,
    const float* __restrict__ g_g, const float* __restrict__ a_g,
    const float* __restrict__ m_g, const float* __restrict__ m0g,
    const float* __restrict__ n0g,
    const float* __restrict__ gamma, __bf16* __restrict__ hout) {
  __shared__ __bf16 Ps[64*72];
  __shared__ float g_l[64], n0_l[64], a_l[64], m_l[64], cI_l[64];
  __shared__ float qnA_p[4][64], qnI_l[64], lnS_p[4][64], lnQ_p[4][64];

  const int task = blockIdx.x;
  const int bh = task >> 4, c = task & 15;
  const int b = bh >> 3, h = bh & 7;
  const int t = threadIdx.x;
  const int w = t >> 6, lane = t & 63;
  const int fr = lane & 15, lg = lane >> 4;
  const int jt = w >> 2, sl = w & 3;
  const int row0 = b*NS + c*CHUNK;
  const __bf16* vtb = vT + (size_t)task * 8192;
  const __bf16* c0b = C0T + (size_t)task * 8192;

  const float m0v = m0g[bh*NCHUNK + c];
  if (t < 64) {
    g_l[t]  = g_g[bh*NS + c*CHUNK + t];
    n0_l[t] = n0g[task*64 + t];
  } else if (t < 128) {
    int jl = t - 64;
    float av = a_g[bh*NS + c*CHUNK + jl];
    a_l[jl] = av;
    m_l[jl] = m_g[bh*NS + c*CHUNK + jl];
    cI_l[jl] = __expf(m0v - av);
  }
  __syncthreads();

  // ---- q frags (rows jt*16 + fr), register-resident
  const int Ra = jt*16 + fr;
  const size_t qrow = (size_t)(row0 + Ra)*512 + h*64;
  bf16x8 qhv[2], qlv[2];
  #pragma unroll
  for (int kk = 0; kk < 2; ++kk) {
    const int kg = kk*4 + lg;
    const int off = (kg ^ (Ra & 7)) * 8;
    qhv[kk] = *(const bf16x8*)&qh[qrow + off];
    qlv[kk] = *(const bf16x8*)&ql[qrow + off];
  }

  // ---- Phase A: this wave's S-tile (jt, st=sl), hi/lo, mask+exp, P->bf16
  float rsum[4] = {0.f, 0.f, 0.f, 0.f};
  if (sl <= jt) {
    f32x4 sacc = {};
    const int Rb = sl*16 + fr;
    const size_t krow = (size_t)(row0 + Rb)*512 + h*64;
    #pragma unroll
    for (int kk = 0; kk < 2; ++kk) {
      const int kg = kk*4 + lg;
      const int offb = (kg ^ (Rb & 7)) * 8;
      bf16x8 khv = *(const bf16x8*)&kh[krow + offb];
      bf16x8 klv = *(const bf16x8*)&kl[krow + offb];
      sacc = __builtin_amdgcn_mfma_f32_16x16x32_bf16(qhv[kk], khv, sacc, 0, 0, 0);
      sacc = __builtin_amdgcn_mfma_f32_16x16x32_bf16(qhv[kk], klv, sacc, 0, 0, 0);
      sacc = __builtin_amdgcn_mfma_f32_16x16x32_bf16(qlv[kk], khv, sacc, 0, 0, 0);
    }
    const int s_c = sl*16 + fr;
    const float gs = g_l[s_c];
    #pragma unroll
    for (int r = 0; r < 4; ++r) {
      const int jl = jt*16 + lg*4 + r;
      float wgt = (s_c <= jl) ? __expf(gs - a_l[jl]) : 0.f;
      float p = sacc[r] * wgt;
      rsum[r] += p;
      Ps[jl*72 + s_c] = (__bf16)p;
    }
  } else {
    #pragma unroll
    for (int r = 0; r < 4; ++r)
      Ps[(jt*16 + lg*4 + r)*72 + sl*16 + fr] = (__bf16)0.f;
  }
  #pragma unroll
  for (int r = 0; r < 4; ++r) {
    #pragma unroll
    for (int off = 1; off < 16; off <<= 1) rsum[r] += __shfl_xor(rsum[r], off, 64);
  }
  if (fr == 0) {
    #pragma unroll
    for (int r = 0; r < 4; ++r) qnA_p[sl][jt*16 + lg*4 + r] = rsum[r];
  }

  // ---- inter term: acc[j][u] = q_hi . C0T over this wave's 2 u-tiles, * cI[j]
  f32x4 acc[2] = {};
  #pragma unroll
  for (int kk = 0; kk < 2; ++kk) {
    const int kg = kk*4 + lg;
    #pragma unroll
    for (int nt = 0; nt < 2; ++nt) {
      const int Rb = (sl*2 + nt)*16 + fr;
      bf16x8 bc = *(const bf16x8*)&c0b[Rb*64 + ((kg ^ (Rb&7))*8)];
      acc[nt] = __builtin_amdgcn_mfma_f32_16x16x32_bf16(qhv[kk], bc, acc[nt], 0, 0, 0);
    }
  }
  {
    float ci4[4];
    #pragma unroll
    for (int r = 0; r < 4; ++r) ci4[r] = cI_l[jt*16 + lg*4 + r];
    #pragma unroll
    for (int nt = 0; nt < 2; ++nt)
      #pragma unroll
      for (int r = 0; r < 4; ++r) acc[nt][r] *= ci4[r];
  }
  // ---- qn_inter (sl==3 waves; A-idle for jt<3): cI[j] * sum_d q[j][d]*n0[d]
  if (sl == 3) {
    const int jl = jt*16 + fr;
    const size_t qr2 = (size_t)(row0 + jl)*512 + h*64;
    float s = 0.f;
    #pragma unroll
    for (int i = 0; i < 16; ++i) {
      const int d = lg*16 + i;
      const int off = (((d>>3) ^ (jl&7)) << 3) + (d & 7);
      float qv = (float)qh[qr2 + off] + (float)ql[qr2 + off];
      s += qv * n0_l[d];
    }
    s += __shfl_xor(s, 16, 64);
    s += __shfl_xor(s, 32, 64);
    if (lane < 16) qnI_l[jl] = cI_l[jl] * s;
  }
  __syncthreads();   // Ps/qnA/qnI visibility

  // ---- PV: acc += Ps . vT (this wave's 2 u-tiles)
  #pragma unroll
  for (int kk = 0; kk < 2; ++kk) {
    const int kg = kk*4 + lg;
    bf16x8 ap = *(const bf16x8*)&Ps[(jt*16 + fr)*72 + kg*8];
    #pragma unroll
    for (int nt = 0; nt < 2; ++nt) {
      const int Rb = (sl*2 + nt)*16 + fr;
      bf16x8 bv = *(const bf16x8*)&vtb[Rb*64 + ((kg ^ (Rb&7))*8)];
      acc[nt] = __builtin_amdgcn_mfma_f32_16x16x32_bf16(ap, bv, acc[nt], 0, 0, 0);
    }
  }

  // ---- epilogue part 1: denom + LN partials (this wave's 32 u)
  #pragma unroll
  for (int r = 0; r < 4; ++r) {
    const int jl = jt*16 + lg*4 + r;
    float qn = qnA_p[0][jl] + qnA_p[1][jl] + qnA_p[2][jl] + qnA_p[3][jl] + qnI_l[jl];
    float denom = fmaxf(fabsf(qn), __expf(-m_l[jl])) + 1e-6f;
    float rd = 1.f / denom;
    float s = 0.f, q2 = 0.f;
    #pragma unroll
    for (int nt = 0; nt < 2; ++nt) {
      float hv = acc[nt][r] * rd;
      acc[nt][r] = hv;
      s += hv; q2 += hv*hv;
    }
    #pragma unroll
    for (int off = 1; off < 16; off <<= 1) {
      s  += __shfl_xor(s,  off, 64);
      q2 += __shfl_xor(q2, off, 64);
    }
    if (fr == 0) { lnS_p[sl][jl] = s; lnQ_p[sl][jl] = q2; }
  }
  __syncthreads();

  // ---- epilogue part 2: LN + output gate + bf16 store
  #pragma unroll
  for (int r = 0; r < 4; ++r) {
    const int jl = jt*16 + lg*4 + r;
    float sm = lnS_p[0][jl] + lnS_p[1][jl] + lnS_p[2][jl] + lnS_p[3][jl];
    float sq = lnQ_p[0][jl] + lnQ_p[1][jl] + lnQ_p[2][jl] + lnQ_p[3][jl];
    float mu = sm * (1.f/128.f);
    float var = sq * (1.f/128.f) - mu*mu;
    float rstd = rsqrtf(var + 1e-6f);
    const int rowg = row0 + jl;
    #pragma unroll
    for (int nt = 0; nt < 2; ++nt) {
      const int u = (sl*2 + nt)*16 + fr;
      float sg = (float)ogs[(size_t)rowg*1024 + h*DHV + u];
      float hn = (acc[nt][r] - mu) * rstd * gamma[h*DHV + u] * sg;
      hout[(size_t)rowg*NV + h*DHV + u] = (__bf16)hn;
    }
  }
}

extern "C" void kernel_launch(void* const* d_in, const int* in_sizes, int n_in,
                              void* d_out, int out_size, void* d_ws, size_t ws_size,
                              hipStream_t stream) {
  const float* x    = (const float*)d_in[0];
  const float* Wq   = (const float*)d_in[1];
  const float* Wk   = (const float*)d_in[2];
  const float* Wv   = (const float*)d_in[3];
  const float* Wog  = (const float*)d_in[4];
  const float* Wi   = (const float*)d_in[5];
  const float* bi   = (const float*)d_in[6];
  const float* Wf   = (const float*)d_in[7];
  const float* bf_  = (const float*)d_in[8];
  const float* gamma= (const float*)d_in[9];
  const float* Wout = (const float*)d_in[10];
  float* y = (float*)d_out;

  char* ws = (char*)d_ws;
  const size_t MB = 1u << 20;
  __bf16*   xb   = (__bf16*)  (ws + 0);        // 4 MB
  __bf16*   Wb   = (__bf16*)  (ws + 4*MB);     // 6 MB
  __bf16*   Wob  = (__bf16*)  (ws + 10*MB);    // 2 MB
  __bf16*   qh   = (__bf16*)  (ws + 12*MB);    // 2 MB  [2048][512] swz
  __bf16*   ql   = (__bf16*)  (ws + 14*MB);    // 2 MB
  __bf16*   kh   = (__bf16*)  (ws + 16*MB);    // 2 MB
  __bf16*   kl   = (__bf16*)  (ws + 18*MB);    // 2 MB
  __bf16*   kT   = (__bf16*)  (ws + 20*MB);    // 2 MB  [256][64][64] swz
  __bf16*   vT   = (__bf16*)  (ws + 22*MB);    // 4 MB  [256][128][64] swz
  _Float16* ogs  = (_Float16*)(ws + 26*MB);    // 4 MB  [2048][1024] sigmoid
  float*    Ut   = (float*)   (ws + 30*MB);    // 8 MB  [256][128][64]
  __bf16*   C0T  = (__bf16*)  (ws + 38*MB);    // 4 MB  [256][128][64] swz
  float*    icap = (float*)   (ws + 42*MB);
  float*    flog = (float*)   (ws + 42*MB + 64*1024);
  float*    g_g  = (float*)   (ws + 42*MB + 128*1024);
  float*    a_g  = (float*)   (ws + 42*MB + 192*1024);
  float*    m_g  = (float*)   (ws + 42*MB + 256*1024);
  float*    m0g  = (float*)   (ws + 42*MB + 320*1024);
  float*    Ung  = (float*)   (ws + 42*MB + 384*1024);
  float*    n0g  = (float*)   (ws + 42*MB + 448*1024);
  __bf16*   houtb= (__bf16*)  (ws + 44*MB);    // 4 MB

  prep_kernel<<<8192, 256, 0, stream>>>(x, Wq, Wk, Wv, Wog, Wout, Wi, bi, Wf, bf_,
                                        xb, Wb, Wob, icap, flog);

  gemm_proj<<<768, 256, 0, stream>>>(xb, Wb, qh, ql, kh, kl, kT, vT, ogs);

  gates_kernel<<<16, 64, 0, stream>>>(icap, flog, g_g, a_g, m_g, m0g);
  u_kernel<<<256, 256, 0, stream>>>(kT, vT, g_g, a_g, Ut, Ung);
  statescan_kernel<<<256, 64, 0, stream>>>(Ut, Ung, m0g, a_g, C0T, n0g);
  intra_kernel<<<256, 1024, 0, stream>>>(qh, ql, kh, kl, vT, C0T, ogs,
                                         g_g, a_g, m_g, m0g, n0g, gamma, houtb);

  gemm_bt<<<512, 256, 0, stream>>>(houtb, Wob, y, 2048, 1024, 1024, 16, 512);
}